// Round 1
// baseline (1011.484 us; speedup 1.0000x reference)
//
#include <hip/hip_runtime.h>
#include <math.h>

#define NNODES 50000
#define NEDGES 800000
#define DIN 256
#define DHID 128

// ---------------- CSR build ----------------
__global__ __launch_bounds__(256) void k_hist(const int* __restrict__ dst, int* __restrict__ counts) {
    int e = blockIdx.x * 256 + threadIdx.x;
    if (e < NEDGES) atomicAdd(&counts[dst[e]], 1);
}

// inclusive scan of counts -> row_ptr+1 ; per-block totals -> partials
__global__ __launch_bounds__(256) void k_scan_block(const int* __restrict__ in, int* __restrict__ out,
                                                    int* __restrict__ partials, int n) {
    __shared__ int sh[256];
    int tid = threadIdx.x;
    int i = blockIdx.x * 256 + tid;
    int vv = (i < n) ? in[i] : 0;
    sh[tid] = vv;
    __syncthreads();
    for (int off = 1; off < 256; off <<= 1) {
        int t = (tid >= off) ? sh[tid - off] : 0;
        __syncthreads();
        sh[tid] += t;
        __syncthreads();
    }
    if (i < n) out[i] = sh[tid];
    if (tid == 255) partials[blockIdx.x] = sh[255];
}

__global__ __launch_bounds__(256) void k_scan_partials(int* __restrict__ partials, int nb) {
    __shared__ int sh[256];
    int tid = threadIdx.x;
    int vv = (tid < nb) ? partials[tid] : 0;
    sh[tid] = vv;
    __syncthreads();
    for (int off = 1; off < 256; off <<= 1) {
        int t = (tid >= off) ? sh[tid - off] : 0;
        __syncthreads();
        sh[tid] += t;
        __syncthreads();
    }
    if (tid < nb) partials[tid] = sh[tid];
}

__global__ __launch_bounds__(256) void k_apply(const int* __restrict__ partials, int* __restrict__ row_ptr, int n) {
    int i = blockIdx.x * 256 + threadIdx.x;
    if (i < n) {
        int add = blockIdx.x ? partials[blockIdx.x - 1] : 0;
        row_ptr[i + 1] += add;
    }
    if (i == 0) row_ptr[0] = 0;
}

__global__ __launch_bounds__(256) void k_scatter(const int* __restrict__ dst, const int* __restrict__ row_ptr,
                                                 int* __restrict__ fill, int* __restrict__ eids) {
    int e = blockIdx.x * 256 + threadIdx.x;
    if (e < NEDGES) {
        int d = dst[e];
        int pos = row_ptr[d] + atomicAdd(&fill[d], 1);
        eids[pos] = e;
    }
}

// ---------------- tiled fp32 GEMM: C[M,128] = A[M,K] @ W[K,128] + b ----------------
template <int K>
__global__ __launch_bounds__(256) void gemm_f32(const float* __restrict__ A, const float* __restrict__ W,
                                                const float* __restrict__ bias, float* __restrict__ C, int M) {
    __shared__ __align__(16) float As[16][68];   // [kk][row], stride 68 (16B-aligned rows, low conflicts)
    __shared__ __align__(16) float Ws[16][128];  // [kk][col]
    const int tid = threadIdx.x;
    const int row0 = blockIdx.x * 64;
    const int tc = tid & 31;   // col group: cols [tc*4, tc*4+4)
    const int tr = tid >> 5;   // row group: rows [tr*8, tr*8+8)
    float acc[8][4];
#pragma unroll
    for (int i = 0; i < 8; i++)
#pragma unroll
        for (int j = 0; j < 4; j++) acc[i][j] = 0.f;

    const int ar = tid >> 2;          // row this thread stages (0..63)
    const int ak = (tid & 3) * 4;     // k offset this thread stages
    const int grow = row0 + ar;

    for (int k0 = 0; k0 < K; k0 += 16) {
        float4 av = make_float4(0.f, 0.f, 0.f, 0.f);
        if (grow < M) av = *(const float4*)(A + (size_t)grow * K + k0 + ak);
        As[ak + 0][ar] = av.x;
        As[ak + 1][ar] = av.y;
        As[ak + 2][ar] = av.z;
        As[ak + 3][ar] = av.w;
        const float4* Wg = (const float4*)(W + (size_t)k0 * 128);
        float4* WsV = (float4*)(&Ws[0][0]);
        WsV[tid] = Wg[tid];
        WsV[tid + 256] = Wg[tid + 256];
        __syncthreads();
#pragma unroll
        for (int kk = 0; kk < 16; ++kk) {
            float4 a0 = *(const float4*)(&As[kk][tr * 8]);
            float4 a1 = *(const float4*)(&As[kk][tr * 8 + 4]);
            float4 w = *(const float4*)(&Ws[kk][tc * 4]);
            float a[8] = {a0.x, a0.y, a0.z, a0.w, a1.x, a1.y, a1.z, a1.w};
#pragma unroll
            for (int i = 0; i < 8; i++) {
                acc[i][0] += a[i] * w.x;
                acc[i][1] += a[i] * w.y;
                acc[i][2] += a[i] * w.z;
                acc[i][3] += a[i] * w.w;
            }
        }
        __syncthreads();
    }
    float4 bv = *(const float4*)(bias + tc * 4);
#pragma unroll
    for (int i = 0; i < 8; i++) {
        int r = row0 + tr * 8 + i;
        if (r < M) {
            float4 o = make_float4(acc[i][0] + bv.x, acc[i][1] + bv.y, acc[i][2] + bv.z, acc[i][3] + bv.w);
            *(float4*)(C + (size_t)r * 128 + tc * 4) = o;
        }
    }
}

// ---------------- per-node fused attention (one wave per node, online softmax) ----------------
// NOTE: agg may alias q (q row is read before agg row is written, same owner wave) -> no __restrict__ on q/agg.
__global__ __launch_bounds__(256) void node_attn(const float* q, const float* __restrict__ k,
                                                 const float* __restrict__ v, const int* __restrict__ src,
                                                 const float* __restrict__ ea, const float* __restrict__ We,
                                                 const int* __restrict__ row_ptr, const int* __restrict__ eids,
                                                 float* agg) {
    const int wid = (blockIdx.x * blockDim.x + threadIdx.x) >> 6;
    const int lane = threadIdx.x & 63;
    if (wid >= NNODES) return;
    const int base = row_ptr[wid];
    const int end = row_ptr[wid + 1];
    const float we0 = We[lane], we1 = We[lane + 64];
    const float qc0 = q[(size_t)wid * 128 + lane];
    const float qc1 = q[(size_t)wid * 128 + 64 + lane];
    float m_a = -INFINITY, m_b = -INFINITY;
    float s_a = 0.f, s_b = 0.f;
    float acc0 = 0.f, acc1 = 0.f;
    const float rsc = 0.17677669529663689f;  // 1/sqrt(32)

    for (int cbase = base; cbase < end; cbase += 64) {
        int rem = end - cbase;
        int cnt = rem < 64 ? rem : 64;
        int s_l = 0;
        float a_l = 0.f;
        if (lane < cnt) {
            int e = eids[cbase + lane];
            s_l = src[e];
            a_l = ea[e];
        }
        for (int j = 0; j < cnt; ++j) {
            int sN = __shfl(s_l, j);
            float av = __shfl(a_l, j);
            const float* kr = k + (size_t)sN * 128;
            const float* vr = v + (size_t)sN * 128;
            float kj0 = kr[lane] + av * we0;
            float kj1 = kr[64 + lane] + av * we1;
            float vj0 = vr[lane] + av * we0;
            float vj1 = vr[64 + lane] + av * we1;
            float p0 = qc0 * kj0, p1 = qc1 * kj1;
#pragma unroll
            for (int off = 16; off; off >>= 1) {
                p0 += __shfl_xor(p0, off);
                p1 += __shfl_xor(p1, off);
            }
            p0 *= rsc;
            p1 *= rsc;
            // online softmax update, head a = lane/32, head b = 2 + lane/32
            float mna = fmaxf(m_a, p0);
            float wa = __expf(p0 - mna);
            float sca = __expf(m_a - mna);
            s_a = s_a * sca + wa;
            acc0 = acc0 * sca + wa * vj0;
            m_a = mna;
            float mnb = fmaxf(m_b, p1);
            float wb = __expf(p1 - mnb);
            float scb = __expf(m_b - mnb);
            s_b = s_b * scb + wb;
            acc1 = acc1 * scb + wb * vj1;
            m_b = mnb;
        }
    }
    agg[(size_t)wid * 128 + lane] = acc0 / (s_a + 1e-16f);
    agg[(size_t)wid * 128 + 64 + lane] = acc1 / (s_b + 1e-16f);
}

// ---------------- fused beta-gate + GELU + LayerNorm (one wave per node) ----------------
__global__ __launch_bounds__(256) void fuse_out(const float* __restrict__ agg, const float* __restrict__ xr,
                                                const float* res, const float* __restrict__ Wb,
                                                const float* __restrict__ lng, const float* __restrict__ lnb,
                                                float* hout) {
    const int wid = (blockIdx.x * blockDim.x + threadIdx.x) >> 6;
    const int lane = threadIdx.x & 63;
    if (wid >= NNODES) return;
    size_t o = (size_t)wid * 128;
    float o0 = agg[o + lane], o1 = agg[o + 64 + lane];
    float x0 = xr[o + lane], x1 = xr[o + 64 + lane];
    float bl = o0 * Wb[lane] + o1 * Wb[64 + lane] + x0 * Wb[128 + lane] + x1 * Wb[192 + lane] +
               (o0 - x0) * Wb[256 + lane] + (o1 - x1) * Wb[320 + lane];
#pragma unroll
    for (int off = 32; off; off >>= 1) bl += __shfl_xor(bl, off);
    float beta = 1.f / (1.f + __expf(-bl));
    float g0 = beta * x0 + (1.f - beta) * o0;
    float g1 = beta * x1 + (1.f - beta) * o1;
    g0 = 0.5f * g0 * (1.f + erff(g0 * 0.70710678118654752f));
    g1 = 0.5f * g1 * (1.f + erff(g1 * 0.70710678118654752f));
    float t0 = g0 + res[o + lane];
    float t1 = g1 + res[o + 64 + lane];
    float su = t0 + t1, sq = t0 * t0 + t1 * t1;
#pragma unroll
    for (int off = 32; off; off >>= 1) {
        su += __shfl_xor(su, off);
        sq += __shfl_xor(sq, off);
    }
    float mu = su * (1.f / 128.f);
    float var = sq * (1.f / 128.f) - mu * mu;
    float inv = rsqrtf(var + 1e-5f);
    hout[o + lane] = (t0 - mu) * inv * lng[lane] + lnb[lane];
    hout[o + 64 + lane] = (t1 - mu) * inv * lng[64 + lane] + lnb[64 + lane];
}

extern "C" void kernel_launch(void* const* d_in, const int* in_sizes, int n_in, void* d_out, int out_size,
                              void* d_ws, size_t ws_size, hipStream_t stream) {
    const float* x = (const float*)d_in[0];
    const int* ei = (const int*)d_in[1];
    const float* ea = (const float*)d_in[2];
    const float* Wi = (const float*)d_in[3];
    const float* bi = (const float*)d_in[4];
    const float* Wq = (const float*)d_in[5];
    const float* bq = (const float*)d_in[6];
    const float* Wk = (const float*)d_in[7];
    const float* bk = (const float*)d_in[8];
    const float* Wv = (const float*)d_in[9];
    const float* bv = (const float*)d_in[10];
    const float* We = (const float*)d_in[11];
    const float* Wskip = (const float*)d_in[12];
    const float* bskip = (const float*)d_in[13];
    const float* Wbeta = (const float*)d_in[14];
    const float* lng = (const float*)d_in[15];
    const float* lnb = (const float*)d_in[16];

    const int* srcp = ei;
    const int* dstp = ei + NEDGES;

    char* p = (char*)d_ws;
    auto alloc = [&](size_t bytes) {
        void* r = (void*)p;
        p += (bytes + 255) & ~(size_t)255;
        return r;
    };
    float* h = (float*)alloc((size_t)NNODES * 128 * 4);
    float* q = (float*)alloc((size_t)NNODES * 128 * 4);
    float* k = (float*)alloc((size_t)NNODES * 128 * 4);
    float* v = (float*)alloc((size_t)NNODES * 128 * 4);
    float* xr = (float*)alloc((size_t)NNODES * 128 * 4);
    int* counts = (int*)alloc((size_t)NNODES * 4);
    int* row_ptr = (int*)alloc((size_t)(NNODES + 1) * 4);
    int* eids = (int*)alloc((size_t)NEDGES * 4);
    int* partials = (int*)alloc(256 * 4);
    float* agg = q;  // safe alias: q row read before agg row written by the same wave

    const int EB = (NEDGES + 255) / 256;       // 3125
    const int NB = (NNODES + 255) / 256;       // 196
    const int GB = (NNODES + 63) / 64;         // 782
    const int WB = (NNODES * 64 + 255) / 256;  // 12500

    // CSR by dst (rebuilt every call; edge_index is constant input)
    hipMemsetAsync(counts, 0, (size_t)NNODES * 4, stream);
    k_hist<<<EB, 256, 0, stream>>>(dstp, counts);
    k_scan_block<<<NB, 256, 0, stream>>>(counts, row_ptr + 1, partials, NNODES);
    k_scan_partials<<<1, 256, 0, stream>>>(partials, NB);
    k_apply<<<NB, 256, 0, stream>>>(partials, row_ptr, NNODES);
    hipMemsetAsync(counts, 0, (size_t)NNODES * 4, stream);
    k_scatter<<<EB, 256, 0, stream>>>(dstp, row_ptr, counts, eids);

    // input projection
    gemm_f32<DIN><<<GB, 256, 0, stream>>>(x, Wi, bi, h, NNODES);

    for (int l = 0; l < 3; ++l) {
        const size_t wo = (size_t)l * 128 * 128;
        const size_t bo = (size_t)l * 128;
        gemm_f32<DHID><<<GB, 256, 0, stream>>>(h, Wq + wo, bq + bo, q, NNODES);
        gemm_f32<DHID><<<GB, 256, 0, stream>>>(h, Wk + wo, bk + bo, k, NNODES);
        gemm_f32<DHID><<<GB, 256, 0, stream>>>(h, Wv + wo, bv + bo, v, NNODES);
        gemm_f32<DHID><<<GB, 256, 0, stream>>>(h, Wskip + wo, bskip + bo, xr, NNODES);
        node_attn<<<WB, 256, 0, stream>>>(q, k, v, srcp, ea, We + bo, row_ptr, eids, agg);
        fuse_out<<<WB, 256, 0, stream>>>(agg, xr, h, Wbeta + (size_t)l * 384, lng + bo, lnb + bo,
                                         (l == 2) ? (float*)d_out : h);
    }
}

// Round 2
// 670.246 us; speedup vs baseline: 1.5091x; 1.5091x over previous
//
#include <hip/hip_runtime.h>
#include <math.h>

#define NNODES 50000
#define NEDGES 800000
#define DIN 256
#define DHID 128

typedef __attribute__((ext_vector_type(8))) short short8;
typedef __attribute__((ext_vector_type(4))) float f32x4;

__device__ __forceinline__ unsigned short f2bf(float f) {
    unsigned u = __builtin_bit_cast(unsigned, f);
    u += 0x7fffu + ((u >> 16) & 1u);  // RNE
    return (unsigned short)(u >> 16);
}
__device__ __forceinline__ float bf2f(unsigned short s) {
    return __builtin_bit_cast(float, (unsigned)s << 16);
}

// ---------------- CSR build ----------------
__global__ __launch_bounds__(256) void k_hist(const int* __restrict__ dst, int* __restrict__ counts) {
    int e = blockIdx.x * 256 + threadIdx.x;
    if (e < NEDGES) atomicAdd(&counts[dst[e]], 1);
}

__global__ __launch_bounds__(256) void k_scan_block(const int* __restrict__ in, int* __restrict__ out,
                                                    int* __restrict__ partials, int n) {
    __shared__ int sh[256];
    int tid = threadIdx.x;
    int i = blockIdx.x * 256 + tid;
    int vv = (i < n) ? in[i] : 0;
    sh[tid] = vv;
    __syncthreads();
    for (int off = 1; off < 256; off <<= 1) {
        int t = (tid >= off) ? sh[tid - off] : 0;
        __syncthreads();
        sh[tid] += t;
        __syncthreads();
    }
    if (i < n) out[i] = sh[tid];
    if (tid == 255) partials[blockIdx.x] = sh[255];
}

__global__ __launch_bounds__(256) void k_scan_partials(int* __restrict__ partials, int nb) {
    __shared__ int sh[256];
    int tid = threadIdx.x;
    int vv = (tid < nb) ? partials[tid] : 0;
    sh[tid] = vv;
    __syncthreads();
    for (int off = 1; off < 256; off <<= 1) {
        int t = (tid >= off) ? sh[tid - off] : 0;
        __syncthreads();
        sh[tid] += t;
        __syncthreads();
    }
    if (tid < nb) partials[tid] = sh[tid];
}

__global__ __launch_bounds__(256) void k_apply(const int* __restrict__ partials, int* __restrict__ row_ptr, int n) {
    int i = blockIdx.x * 256 + threadIdx.x;
    if (i < n) {
        int add = blockIdx.x ? partials[blockIdx.x - 1] : 0;
        row_ptr[i + 1] += add;
    }
    if (i == 0) row_ptr[0] = 0;
}

__global__ __launch_bounds__(256) void k_scatter(const int* __restrict__ dst, const int* __restrict__ row_ptr,
                                                 int* __restrict__ fill, int* __restrict__ eids) {
    int e = blockIdx.x * 256 + threadIdx.x;
    if (e < NEDGES) {
        int d = dst[e];
        int pos = row_ptr[d] + atomicAdd(&fill[d], 1);
        eids[pos] = e;
    }
}

// ---------------- weight prep: transpose + bf16 cast ----------------
__global__ __launch_bounds__(256) void prep_wi(const float* __restrict__ Wi, unsigned short* __restrict__ Wit) {
    int idx = blockIdx.x * 256 + threadIdx.x;  // n*256 + k
    if (idx >= DHID * DIN) return;
    int n = idx >> 8, kk = idx & 255;
    Wit[idx] = f2bf(Wi[kk * DHID + n]);
}

// Wt3[l][512][128]: rows 0-127 Wq^T, 128-255 Wk^T, 256-383 Wv^T, 384-511 Wskip^T
__global__ __launch_bounds__(256) void prep_wqkvs(const float* __restrict__ Wq, const float* __restrict__ Wk,
                                                  const float* __restrict__ Wv, const float* __restrict__ Ws,
                                                  unsigned short* __restrict__ out) {
    int idx = blockIdx.x * 256 + threadIdx.x;
    if (idx >= 3 * 512 * DHID) return;
    int l = idx / (512 * DHID);
    int rem = idx - l * 512 * DHID;
    int r = rem >> 7;   // 0..511
    int kk = rem & 127;
    int sel = r >> 7, rl = r & 127;
    const float* srcm = sel == 0 ? Wq : sel == 1 ? Wk : sel == 2 ? Wv : Ws;
    out[idx] = f2bf(srcm[l * DHID * DHID + kk * DHID + rl]);
}

// ---------------- input projection: h[M,128] = x[M,256] @ Wi + bi (bf16 MFMA) ----------------
__global__ __launch_bounds__(256) void gemm_in(const float* __restrict__ A, const unsigned short* __restrict__ Wt,
                                               const float* __restrict__ bias, float* __restrict__ C, int M) {
    __shared__ short As[128 * 128];  // swizzled bf16 tile
    const int tid = threadIdx.x;
    const int lane = tid & 63;
    const int wid = tid >> 6;
    const int row0 = blockIdx.x * 128;
    const int wr = (wid & 1) * 64;
    const int wc = (wid >> 1) * 64;
    f32x4 acc[4][4] = {};
    const int srow = tid >> 1;
    const int sk = (tid & 1) * 64;
    const int grow = min(row0 + srow, M - 1);
    for (int kt = 0; kt < 2; ++kt) {
        const float* ap = A + (size_t)grow * DIN + kt * 128 + sk;
#pragma unroll
        for (int i = 0; i < 8; ++i) {
            float4 f0 = *(const float4*)(ap + i * 8);
            float4 f1 = *(const float4*)(ap + i * 8 + 4);
            short8 s;
            s[0] = f2bf(f0.x); s[1] = f2bf(f0.y); s[2] = f2bf(f0.z); s[3] = f2bf(f0.w);
            s[4] = f2bf(f1.x); s[5] = f2bf(f1.y); s[6] = f2bf(f1.z); s[7] = f2bf(f1.w);
            int g = (sk + i * 8) >> 3;
            *(short8*)(&As[srow * 128 + ((g ^ (srow & 7)) << 3)]) = s;
        }
        __syncthreads();
#pragma unroll
        for (int ks = 0; ks < 4; ++ks) {
            short8 a[4], b[4];
#pragma unroll
            for (int m = 0; m < 4; ++m) {
                int r = wr + m * 16 + (lane & 15);
                int g = (ks * 32 + (lane >> 4) * 8) >> 3;
                a[m] = *(const short8*)(&As[r * 128 + ((g ^ (r & 7)) << 3)]);
            }
#pragma unroll
            for (int n = 0; n < 4; ++n) {
                int c = wc + n * 16 + (lane & 15);
                b[n] = *(const short8*)(Wt + (size_t)c * DIN + kt * 128 + ks * 32 + (lane >> 4) * 8);
            }
#pragma unroll
            for (int m = 0; m < 4; ++m)
#pragma unroll
                for (int n = 0; n < 4; ++n)
                    acc[m][n] = __builtin_amdgcn_mfma_f32_16x16x32_bf16(a[m], b[n], acc[m][n], 0, 0, 0);
        }
        __syncthreads();
    }
#pragma unroll
    for (int n = 0; n < 4; ++n) {
        int c = wc + n * 16 + (lane & 15);
        float bb = bias[c];
#pragma unroll
        for (int m = 0; m < 4; ++m)
#pragma unroll
            for (int j = 0; j < 4; ++j) {
                int r = row0 + wr + m * 16 + (lane >> 4) * 4 + j;
                if (r < M) C[(size_t)r * DHID + c] = acc[m][n][j] + bb;
            }
    }
}

// ---------------- fused q/k/v/skip GEMM: [M,512] = h[M,128] @ Wt3[l]^T (bf16 MFMA) ----------------
// 8 waves: wave computes 64 rows x 128 cols; wcol selects output tensor (0=q f32, 1=k bf16, 2=v bf16, 3=xr f32)
__global__ __launch_bounds__(512) void gemm_qkvs(const float* __restrict__ A, const unsigned short* __restrict__ Wt,
                                                 const float* __restrict__ bq, const float* __restrict__ bk,
                                                 const float* __restrict__ bv, const float* __restrict__ bs,
                                                 float* __restrict__ q, unsigned short* __restrict__ k,
                                                 unsigned short* __restrict__ v, float* __restrict__ xr, int M) {
    __shared__ short As[128 * 128];
    const int tid = threadIdx.x;
    const int lane = tid & 63;
    const int wid = tid >> 6;
    const int row0 = blockIdx.x * 128;
    const int wr = (wid & 1) * 64;
    const int wcol = wid >> 1;  // 0..3
    f32x4 acc[4][8] = {};
    {
        const int srow = tid >> 2;
        const int sk = (tid & 3) * 32;
        const int grow = min(row0 + srow, M - 1);
        const float* ap = A + (size_t)grow * DHID + sk;
#pragma unroll
        for (int i = 0; i < 4; ++i) {
            float4 f0 = *(const float4*)(ap + i * 8);
            float4 f1 = *(const float4*)(ap + i * 8 + 4);
            short8 s;
            s[0] = f2bf(f0.x); s[1] = f2bf(f0.y); s[2] = f2bf(f0.z); s[3] = f2bf(f0.w);
            s[4] = f2bf(f1.x); s[5] = f2bf(f1.y); s[6] = f2bf(f1.z); s[7] = f2bf(f1.w);
            int g = (sk + i * 8) >> 3;
            *(short8*)(&As[srow * 128 + ((g ^ (srow & 7)) << 3)]) = s;
        }
    }
    __syncthreads();
#pragma unroll
    for (int ks = 0; ks < 4; ++ks) {
        short8 a[4], b[8];
#pragma unroll
        for (int m = 0; m < 4; ++m) {
            int r = wr + m * 16 + (lane & 15);
            int g = (ks * 32 + (lane >> 4) * 8) >> 3;
            a[m] = *(const short8*)(&As[r * 128 + ((g ^ (r & 7)) << 3)]);
        }
#pragma unroll
        for (int n = 0; n < 8; ++n) {
            int c = wcol * 128 + n * 16 + (lane & 15);
            b[n] = *(const short8*)(Wt + (size_t)c * DHID + ks * 32 + (lane >> 4) * 8);
        }
#pragma unroll
        for (int m = 0; m < 4; ++m)
#pragma unroll
            for (int n = 0; n < 8; ++n)
                acc[m][n] = __builtin_amdgcn_mfma_f32_16x16x32_bf16(a[m], b[n], acc[m][n], 0, 0, 0);
    }
    const float* bias = wcol == 0 ? bq : wcol == 1 ? bk : wcol == 2 ? bv : bs;
#pragma unroll
    for (int n = 0; n < 8; ++n) {
        int c = n * 16 + (lane & 15);
        float bb = bias[c];
#pragma unroll
        for (int m = 0; m < 4; ++m)
#pragma unroll
            for (int j = 0; j < 4; ++j) {
                int r = row0 + wr + m * 16 + (lane >> 4) * 4 + j;
                if (r < M) {
                    float val = acc[m][n][j] + bb;
                    if (wcol == 0) q[(size_t)r * DHID + c] = val;
                    else if (wcol == 1) k[(size_t)r * DHID + c] = f2bf(val);
                    else if (wcol == 2) v[(size_t)r * DHID + c] = f2bf(val);
                    else xr[(size_t)r * DHID + c] = val;
                }
            }
    }
}

// ---------------- per-node attention + beta-gate + GELU + LayerNorm (one wave per node) ----------------
// lane owns channels (2*lane, 2*lane+1); head = lane>>4. k/v are bf16. hout may alias res/q/xr row (same-wave RAW only).
__global__ __launch_bounds__(256) void node_attn_fuse(const float* q, const unsigned short* __restrict__ k,
                                                      const unsigned short* __restrict__ v,
                                                      const int* __restrict__ src, const float* __restrict__ ea,
                                                      const float* __restrict__ We, const int* __restrict__ row_ptr,
                                                      const int* __restrict__ eids, const float* xr, const float* res,
                                                      const float* __restrict__ Wb, const float* __restrict__ lng,
                                                      const float* __restrict__ lnb, float* hout) {
    const int wid = (blockIdx.x * blockDim.x + threadIdx.x) >> 6;
    const int lane = threadIdx.x & 63;
    if (wid >= NNODES) return;
    const int base = row_ptr[wid], end = row_ptr[wid + 1];
    const int c0 = 2 * lane;
    const float2 wev = *(const float2*)(We + c0);
    const float2 qv = *(const float2*)(q + (size_t)wid * 128 + c0);
    float m = -INFINITY, sden = 0.f, acc0 = 0.f, acc1 = 0.f;
    const float rsc = 0.17677669529663689f;  // 1/sqrt(32)
    for (int cb = base; cb < end; cb += 64) {
        int cnt = min(end - cb, 64);
        int s_l = 0;
        float a_l = 0.f;
        if (lane < cnt) {
            int e = eids[cb + lane];
            s_l = src[e];
            a_l = ea[e];
        }
        for (int j = 0; j < cnt; ++j) {
            int sN = __shfl(s_l, j);
            float av = __shfl(a_l, j);
            unsigned kw = *(const unsigned*)(k + (size_t)sN * 128 + c0);
            unsigned vw = *(const unsigned*)(v + (size_t)sN * 128 + c0);
            float kj0 = bf2f((unsigned short)kw) + av * wev.x;
            float kj1 = bf2f((unsigned short)(kw >> 16)) + av * wev.y;
            float vj0 = bf2f((unsigned short)vw) + av * wev.x;
            float vj1 = bf2f((unsigned short)(vw >> 16)) + av * wev.y;
            float p = qv.x * kj0 + qv.y * kj1;
            p += __shfl_xor(p, 1);
            p += __shfl_xor(p, 2);
            p += __shfl_xor(p, 4);
            p += __shfl_xor(p, 8);
            p *= rsc;
            float mn = fmaxf(m, p);
            float w = __expf(p - mn);
            float sc = __expf(m - mn);
            sden = sden * sc + w;
            acc0 = acc0 * sc + w * vj0;
            acc1 = acc1 * sc + w * vj1;
            m = mn;
        }
    }
    float o0 = acc0 / (sden + 1e-16f), o1 = acc1 / (sden + 1e-16f);
    const size_t o = (size_t)wid * 128;
    const float2 xv = *(const float2*)(xr + o + c0);
    const float2 w0 = *(const float2*)(Wb + c0);
    const float2 w1 = *(const float2*)(Wb + 128 + c0);
    const float2 w2 = *(const float2*)(Wb + 256 + c0);
    float bl = o0 * w0.x + o1 * w0.y + xv.x * w1.x + xv.y * w1.y + (o0 - xv.x) * w2.x + (o1 - xv.y) * w2.y;
#pragma unroll
    for (int off = 32; off; off >>= 1) bl += __shfl_xor(bl, off);
    float beta = 1.f / (1.f + __expf(-bl));
    float g0 = beta * xv.x + (1.f - beta) * o0;
    float g1 = beta * xv.y + (1.f - beta) * o1;
    g0 = 0.5f * g0 * (1.f + erff(g0 * 0.70710678118654752f));
    g1 = 0.5f * g1 * (1.f + erff(g1 * 0.70710678118654752f));
    const float2 rv = *(const float2*)(res + o + c0);
    float t0 = g0 + rv.x, t1 = g1 + rv.y;
    float su = t0 + t1, sq = t0 * t0 + t1 * t1;
#pragma unroll
    for (int off = 32; off; off >>= 1) {
        su += __shfl_xor(su, off);
        sq += __shfl_xor(sq, off);
    }
    float mu = su * (1.f / 128.f);
    float var = sq * (1.f / 128.f) - mu * mu;
    float inv = rsqrtf(var + 1e-5f);
    const float2 gv = *(const float2*)(lng + c0);
    const float2 bv2 = *(const float2*)(lnb + c0);
    float2 ov;
    ov.x = (t0 - mu) * inv * gv.x + bv2.x;
    ov.y = (t1 - mu) * inv * gv.y + bv2.y;
    *(float2*)(hout + o + c0) = ov;
}

extern "C" void kernel_launch(void* const* d_in, const int* in_sizes, int n_in, void* d_out, int out_size,
                              void* d_ws, size_t ws_size, hipStream_t stream) {
    const float* x = (const float*)d_in[0];
    const int* ei = (const int*)d_in[1];
    const float* ea = (const float*)d_in[2];
    const float* Wi = (const float*)d_in[3];
    const float* bi = (const float*)d_in[4];
    const float* Wq = (const float*)d_in[5];
    const float* bq = (const float*)d_in[6];
    const float* Wk = (const float*)d_in[7];
    const float* bk = (const float*)d_in[8];
    const float* Wv = (const float*)d_in[9];
    const float* bv = (const float*)d_in[10];
    const float* We = (const float*)d_in[11];
    const float* Wskip = (const float*)d_in[12];
    const float* bskip = (const float*)d_in[13];
    const float* Wbeta = (const float*)d_in[14];
    const float* lng = (const float*)d_in[15];
    const float* lnb = (const float*)d_in[16];

    const int* srcp = ei;
    const int* dstp = ei + NEDGES;

    char* p = (char*)d_ws;
    auto alloc = [&](size_t bytes) {
        void* r = (void*)p;
        p += (bytes + 255) & ~(size_t)255;
        return r;
    };
    float* h = (float*)alloc((size_t)NNODES * 128 * 4);
    float* q = (float*)alloc((size_t)NNODES * 128 * 4);
    float* xr = (float*)alloc((size_t)NNODES * 128 * 4);
    unsigned short* kb = (unsigned short*)alloc((size_t)NNODES * 128 * 2);
    unsigned short* vb = (unsigned short*)alloc((size_t)NNODES * 128 * 2);
    unsigned short* Wit = (unsigned short*)alloc((size_t)DHID * DIN * 2);
    unsigned short* Wt3 = (unsigned short*)alloc((size_t)3 * 512 * DHID * 2);
    int* counts = (int*)alloc((size_t)NNODES * 4);
    int* row_ptr = (int*)alloc((size_t)(NNODES + 1) * 4);
    int* eids = (int*)alloc((size_t)NEDGES * 4);
    int* partials = (int*)alloc(256 * 4);

    const int EB = (NEDGES + 255) / 256;
    const int NB = (NNODES + 255) / 256;
    const int GB = (NNODES + 127) / 128;       // 391
    const int WB = (NNODES * 64 + 255) / 256;  // 12500

    // weight prep
    prep_wi<<<(DHID * DIN + 255) / 256, 256, 0, stream>>>(Wi, Wit);
    prep_wqkvs<<<(3 * 512 * DHID + 255) / 256, 256, 0, stream>>>(Wq, Wk, Wv, Wskip, Wt3);

    // CSR by dst
    hipMemsetAsync(counts, 0, (size_t)NNODES * 4, stream);
    k_hist<<<EB, 256, 0, stream>>>(dstp, counts);
    k_scan_block<<<NB, 256, 0, stream>>>(counts, row_ptr + 1, partials, NNODES);
    k_scan_partials<<<1, 256, 0, stream>>>(partials, NB);
    k_apply<<<NB, 256, 0, stream>>>(partials, row_ptr, NNODES);
    hipMemsetAsync(counts, 0, (size_t)NNODES * 4, stream);
    k_scatter<<<EB, 256, 0, stream>>>(dstp, row_ptr, counts, eids);

    gemm_in<<<GB, 256, 0, stream>>>(x, Wit, bi, h, NNODES);

    for (int l = 0; l < 3; ++l) {
        const size_t bo = (size_t)l * 128;
        gemm_qkvs<<<GB, 512, 0, stream>>>(h, Wt3 + (size_t)l * 512 * DHID, bq + bo, bk + bo, bv + bo, bskip + bo, q,
                                          kb, vb, xr, NNODES);
        node_attn_fuse<<<WB, 256, 0, stream>>>(q, kb, vb, srcp, ea, We + bo, row_ptr, eids, xr, h,
                                               Wbeta + (size_t)l * 384, lng + bo, lnb + bo,
                                               (l == 2) ? (float*)d_out : h);
    }
}

// Round 3
// 497.386 us; speedup vs baseline: 2.0336x; 1.3475x over previous
//
#include <hip/hip_runtime.h>
#include <math.h>

#define NNODES 50000
#define NEDGES 800000
#define DIN 256
#define DHID 128

typedef __attribute__((ext_vector_type(8))) short short8;
typedef __attribute__((ext_vector_type(4))) float f32x4;
typedef __attribute__((ext_vector_type(2))) float f32x2;

__device__ __forceinline__ unsigned short f2bf(float f) {
    unsigned u = __builtin_bit_cast(unsigned, f);
    u += 0x7fffu + ((u >> 16) & 1u);  // RNE
    return (unsigned short)(u >> 16);
}
__device__ __forceinline__ float bf2f(unsigned short s) {
    return __builtin_bit_cast(float, (unsigned)s << 16);
}
__device__ __forceinline__ unsigned packbf(float a, float b) {
    return (unsigned)f2bf(a) | ((unsigned)f2bf(b) << 16);
}

// ---------------- CSR build ----------------
__global__ __launch_bounds__(256) void k_hist(const int* __restrict__ dst, int* __restrict__ counts) {
    int e = blockIdx.x * 256 + threadIdx.x;
    if (e < NEDGES) atomicAdd(&counts[dst[e]], 1);
}

__global__ __launch_bounds__(256) void k_scan_block(const int* __restrict__ in, int* __restrict__ out,
                                                    int* __restrict__ partials, int n) {
    __shared__ int sh[256];
    int tid = threadIdx.x;
    int i = blockIdx.x * 256 + tid;
    int vv = (i < n) ? in[i] : 0;
    sh[tid] = vv;
    __syncthreads();
    for (int off = 1; off < 256; off <<= 1) {
        int t = (tid >= off) ? sh[tid - off] : 0;
        __syncthreads();
        sh[tid] += t;
        __syncthreads();
    }
    if (i < n) out[i] = sh[tid];
    if (tid == 255) partials[blockIdx.x] = sh[255];
}

__global__ __launch_bounds__(256) void k_scan_partials(int* __restrict__ partials, int nb) {
    __shared__ int sh[256];
    int tid = threadIdx.x;
    int vv = (tid < nb) ? partials[tid] : 0;
    sh[tid] = vv;
    __syncthreads();
    for (int off = 1; off < 256; off <<= 1) {
        int t = (tid >= off) ? sh[tid - off] : 0;
        __syncthreads();
        sh[tid] += t;
        __syncthreads();
    }
    if (tid < nb) partials[tid] = sh[tid];
}

__global__ __launch_bounds__(256) void k_apply(const int* __restrict__ partials, int* __restrict__ row_ptr, int n) {
    int i = blockIdx.x * 256 + threadIdx.x;
    if (i < n) {
        int add = blockIdx.x ? partials[blockIdx.x - 1] : 0;
        row_ptr[i + 1] += add;
    }
    if (i == 0) row_ptr[0] = 0;
}

// dst-sorted (src, ea) pairs
__global__ __launch_bounds__(256) void k_scatter(const int* __restrict__ src, const int* __restrict__ dst,
                                                 const float* __restrict__ ea, const int* __restrict__ row_ptr,
                                                 int* __restrict__ fill, int2* __restrict__ esrc) {
    int e = blockIdx.x * 256 + threadIdx.x;
    if (e < NEDGES) {
        int d = dst[e];
        int pos = row_ptr[d] + atomicAdd(&fill[d], 1);
        esrc[pos] = make_int2(src[e], __float_as_int(ea[e]));
    }
}

// ---------------- weight prep: transpose + bf16 cast ----------------
__global__ __launch_bounds__(256) void prep_wi(const float* __restrict__ Wi, unsigned short* __restrict__ Wit) {
    int idx = blockIdx.x * 256 + threadIdx.x;  // n*256 + k
    if (idx >= DHID * DIN) return;
    int n = idx >> 8, kk = idx & 255;
    Wit[idx] = f2bf(Wi[kk * DHID + n]);
}

// Wt3[l][512][128]: rows 0-127 Wq^T, 128-255 Wk^T, 256-383 Wv^T, 384-511 Wskip^T
__global__ __launch_bounds__(256) void prep_wqkvs(const float* __restrict__ Wq, const float* __restrict__ Wk,
                                                  const float* __restrict__ Wv, const float* __restrict__ Ws,
                                                  unsigned short* __restrict__ out) {
    int idx = blockIdx.x * 256 + threadIdx.x;
    if (idx >= 3 * 512 * DHID) return;
    int l = idx / (512 * DHID);
    int rem = idx - l * 512 * DHID;
    int r = rem >> 7;  // 0..511
    int kk = rem & 127;
    int sel = r >> 7, rl = r & 127;
    const float* srcm = sel == 0 ? Wq : sel == 1 ? Wk : sel == 2 ? Wv : Ws;
    out[idx] = f2bf(srcm[l * DHID * DHID + kk * DHID + rl]);
}

// ---------------- input projection: h[M,128](bf16) = x[M,256] @ Wi + bi ----------------
__global__ __launch_bounds__(256) void gemm_in(const float* __restrict__ A, const unsigned short* __restrict__ Wt,
                                               const float* __restrict__ bias, unsigned* __restrict__ h32, int M) {
    __shared__ short As[128 * 128];
    const int tid = threadIdx.x;
    const int lane = tid & 63;
    const int wid = tid >> 6;
    const int row0 = blockIdx.x * 128;
    const int wr = (wid & 1) * 64;
    const int wc = (wid >> 1) * 64;
    f32x4 acc[4][4] = {};
    const int srow = tid >> 1;
    const int sk = (tid & 1) * 64;
    const int grow = min(row0 + srow, M - 1);
    for (int kt = 0; kt < 2; ++kt) {
        const float* ap = A + (size_t)grow * DIN + kt * 128 + sk;
#pragma unroll
        for (int i = 0; i < 8; ++i) {
            float4 f0 = *(const float4*)(ap + i * 8);
            float4 f1 = *(const float4*)(ap + i * 8 + 4);
            short8 s;
            s[0] = f2bf(f0.x); s[1] = f2bf(f0.y); s[2] = f2bf(f0.z); s[3] = f2bf(f0.w);
            s[4] = f2bf(f1.x); s[5] = f2bf(f1.y); s[6] = f2bf(f1.z); s[7] = f2bf(f1.w);
            int g = (sk >> 3) + i;
            *(short8*)(&As[srow * 128 + ((g ^ (srow & 7)) << 3)]) = s;
        }
        __syncthreads();
#pragma unroll
        for (int ks = 0; ks < 4; ++ks) {
            short8 a[4], b[4];
#pragma unroll
            for (int m = 0; m < 4; ++m) {
                int r = wr + m * 16 + (lane & 15);
                int g = ks * 4 + (lane >> 4);
                a[m] = *(const short8*)(&As[r * 128 + ((g ^ (r & 7)) << 3)]);
            }
#pragma unroll
            for (int n = 0; n < 4; ++n) {
                int c = wc + n * 16 + (lane & 15);
                b[n] = *(const short8*)(Wt + (size_t)c * DIN + kt * 128 + ks * 32 + (lane >> 4) * 8);
            }
#pragma unroll
            for (int m = 0; m < 4; ++m)
#pragma unroll
                for (int n = 0; n < 4; ++n)
                    acc[m][n] = __builtin_amdgcn_mfma_f32_16x16x32_bf16(a[m], b[n], acc[m][n], 0, 0, 0);
        }
        __syncthreads();
    }
#pragma unroll
    for (int n = 0; n < 4; ++n) {
        int c = wc + n * 16 + (lane & 15);
        float bb = bias[c];
#pragma unroll
        for (int m = 0; m < 4; ++m)
#pragma unroll
            for (int j = 0; j < 4; ++j) {
                int r = row0 + wr + m * 16 + (lane >> 4) * 4 + j;
                float val = acc[m][n][j] + bb;
                float nb = __shfl_xor(val, 1);
                if (!(lane & 1) && r < M) h32[(size_t)r * 64 + (c >> 1)] = packbf(val, nb);
            }
    }
}

// ---------------- fused q/k/v/skip GEMM from bf16 h ----------------
// 8 waves: (wr, wc) 2x2 tile grid x sel: sel=0 computes q+skip, sel=1 computes k+v (packed fp8 kv)
__global__ __launch_bounds__(512) void gemm_qkvs(const unsigned short* __restrict__ A,
                                                 const unsigned short* __restrict__ Wt, const float* __restrict__ bq,
                                                 const float* __restrict__ bk, const float* __restrict__ bv,
                                                 const float* __restrict__ bs, unsigned* __restrict__ q32,
                                                 unsigned* __restrict__ kv, unsigned* __restrict__ xr32, int M) {
    __shared__ short As[128 * 128];
    const int tid = threadIdx.x;
    const int lane = tid & 63;
    const int wid = tid >> 6;
    const int row0 = blockIdx.x * 128;
    const int sel = wid >> 2;  // 0: q/skip, 1: k/v
    const int wr = (wid & 1) * 64;
    const int wc = ((wid >> 1) & 1) * 64;
    f32x4 acc0[4][4] = {}, acc1[4][4] = {};
    {
        const int srow = tid >> 2;
        const int sk = (tid & 3) * 32;
        const int grow = min(row0 + srow, M - 1);
        const unsigned short* ap = A + (size_t)grow * DHID + sk;
#pragma unroll
        for (int i = 0; i < 4; ++i) {
            short8 s = *(const short8*)(ap + i * 8);
            int g = (sk >> 3) + i;
            *(short8*)(&As[srow * 128 + ((g ^ (srow & 7)) << 3)]) = s;
        }
    }
    __syncthreads();
    const int b0base = sel ? 128 : 0;    // k : q
    const int b1base = sel ? 256 : 384;  // v : skip
#pragma unroll
    for (int ks = 0; ks < 4; ++ks) {
        short8 a[4], b0[4], b1[4];
#pragma unroll
        for (int m = 0; m < 4; ++m) {
            int r = wr + m * 16 + (lane & 15);
            int g = ks * 4 + (lane >> 4);
            a[m] = *(const short8*)(&As[r * 128 + ((g ^ (r & 7)) << 3)]);
        }
#pragma unroll
        for (int n = 0; n < 4; ++n) {
            int rb = wc + n * 16 + (lane & 15);
            b0[n] = *(const short8*)(Wt + (size_t)(b0base + rb) * DHID + ks * 32 + (lane >> 4) * 8);
            b1[n] = *(const short8*)(Wt + (size_t)(b1base + rb) * DHID + ks * 32 + (lane >> 4) * 8);
        }
#pragma unroll
        for (int m = 0; m < 4; ++m)
#pragma unroll
            for (int n = 0; n < 4; ++n) {
                acc0[m][n] = __builtin_amdgcn_mfma_f32_16x16x32_bf16(a[m], b0[n], acc0[m][n], 0, 0, 0);
                acc1[m][n] = __builtin_amdgcn_mfma_f32_16x16x32_bf16(a[m], b1[n], acc1[m][n], 0, 0, 0);
            }
    }
    const float* bias0 = sel ? bk : bq;
    const float* bias1 = sel ? bv : bs;
#pragma unroll
    for (int n = 0; n < 4; ++n) {
        int c = wc + n * 16 + (lane & 15);
        float bb0 = bias0[c];
        float bb1 = bias1[c];
#pragma unroll
        for (int m = 0; m < 4; ++m)
#pragma unroll
            for (int j = 0; j < 4; ++j) {
                int r = row0 + wr + m * 16 + (lane >> 4) * 4 + j;
                float v0 = acc0[m][n][j] + bb0;
                float v1 = acc1[m][n][j] + bb1;
                float n0 = __shfl_xor(v0, 1);
                float n1 = __shfl_xor(v1, 1);
                if (!(lane & 1) && r < M) {
                    if (sel == 0) {
                        q32[(size_t)r * 64 + (c >> 1)] = packbf(v0, n0);
                        xr32[(size_t)r * 64 + (c >> 1)] = packbf(v1, n1);
                    } else {
                        unsigned u = (unsigned)__builtin_amdgcn_cvt_pk_fp8_f32(v0, n0, 0, false);
                        u = (unsigned)__builtin_amdgcn_cvt_pk_fp8_f32(v1, n1, (int)u, true);
                        kv[(size_t)r * 64 + (c >> 1)] = u;
                    }
                }
            }
    }
}

// ---------------- per-node attention + beta-gate + GELU + LayerNorm (one wave per node) ----------------
// lane owns channels (2*lane, 2*lane+1); head = lane>>4. kv fp8-packed. houtb may alias res32 (same-wave RAW only).
__global__ __launch_bounds__(256) void node_attn_fuse(const unsigned* __restrict__ q32,
                                                      const unsigned* __restrict__ kv, const int2* __restrict__ esrc,
                                                      const float* __restrict__ We, const int* __restrict__ row_ptr,
                                                      const unsigned* __restrict__ xr32, const unsigned* res32,
                                                      const float* __restrict__ Wb, const float* __restrict__ lng,
                                                      const float* __restrict__ lnb, unsigned* houtb, float* houtf) {
    const int wid = (blockIdx.x * blockDim.x + threadIdx.x) >> 6;
    const int lane = threadIdx.x & 63;
    if (wid >= NNODES) return;
    const int base = row_ptr[wid], end = row_ptr[wid + 1];
    const int c0 = 2 * lane;
    const float2 wev = *(const float2*)(We + c0);
    const unsigned qw = q32[(size_t)wid * 64 + lane];
    const float q0 = bf2f((unsigned short)qw), q1 = bf2f((unsigned short)(qw >> 16));
    float m = -INFINITY, sden = 0.f, a0 = 0.f, a1 = 0.f;
    const float rsc = 0.17677669529663689f;  // 1/sqrt(32)
    for (int cb = base; cb < end; cb += 64) {
        int cnt = min(end - cb, 64);
        int s_l = 0;
        float a_l = 0.f;
        if (lane < cnt) {
            int2 sa = esrc[cb + lane];
            s_l = sa.x;
            a_l = __int_as_float(sa.y);
        }
        for (int j = 0; j < cnt; ++j) {
            int sN = __shfl(s_l, j);
            float av = __shfl(a_l, j);
            unsigned w = kv[(size_t)sN * 64 + lane];
            f32x2 kk = __builtin_amdgcn_cvt_pk_f32_fp8((int)w, false);
            f32x2 vv = __builtin_amdgcn_cvt_pk_f32_fp8((int)w, true);
            float kj0 = kk.x + av * wev.x, kj1 = kk.y + av * wev.y;
            float vj0 = vv.x + av * wev.x, vj1 = vv.y + av * wev.y;
            float p = q0 * kj0 + q1 * kj1;
            p += __shfl_xor(p, 1);
            p += __shfl_xor(p, 2);
            p += __shfl_xor(p, 4);
            p += __shfl_xor(p, 8);
            p *= rsc;
            float mn = fmaxf(m, p);
            float wgt = __expf(p - mn);
            float sc = __expf(m - mn);
            sden = sden * sc + wgt;
            a0 = a0 * sc + wgt * vj0;
            a1 = a1 * sc + wgt * vj1;
            m = mn;
        }
    }
    float o0 = a0 / (sden + 1e-16f), o1 = a1 / (sden + 1e-16f);
    const unsigned xw = xr32[(size_t)wid * 64 + lane];
    const float x0 = bf2f((unsigned short)xw), x1 = bf2f((unsigned short)(xw >> 16));
    const float2 w0 = *(const float2*)(Wb + c0);
    const float2 w1 = *(const float2*)(Wb + 128 + c0);
    const float2 w2 = *(const float2*)(Wb + 256 + c0);
    float bl = o0 * w0.x + o1 * w0.y + x0 * w1.x + x1 * w1.y + (o0 - x0) * w2.x + (o1 - x1) * w2.y;
#pragma unroll
    for (int off = 32; off; off >>= 1) bl += __shfl_xor(bl, off);
    float beta = 1.f / (1.f + __expf(-bl));
    float g0 = beta * x0 + (1.f - beta) * o0;
    float g1 = beta * x1 + (1.f - beta) * o1;
    g0 = 0.5f * g0 * (1.f + erff(g0 * 0.70710678118654752f));
    g1 = 0.5f * g1 * (1.f + erff(g1 * 0.70710678118654752f));
    const unsigned rw = res32[(size_t)wid * 64 + lane];
    float t0 = g0 + bf2f((unsigned short)rw);
    float t1 = g1 + bf2f((unsigned short)(rw >> 16));
    float su = t0 + t1, sq = t0 * t0 + t1 * t1;
#pragma unroll
    for (int off = 32; off; off >>= 1) {
        su += __shfl_xor(su, off);
        sq += __shfl_xor(sq, off);
    }
    float mu = su * (1.f / 128.f);
    float var = sq * (1.f / 128.f) - mu * mu;
    float inv = rsqrtf(var + 1e-5f);
    const float2 gv = *(const float2*)(lng + c0);
    const float2 bv2 = *(const float2*)(lnb + c0);
    float ov0 = (t0 - mu) * inv * gv.x + bv2.x;
    float ov1 = (t1 - mu) * inv * gv.y + bv2.y;
    if (houtf) {
        *(float2*)(houtf + (size_t)wid * 128 + c0) = make_float2(ov0, ov1);
    } else {
        houtb[(size_t)wid * 64 + lane] = packbf(ov0, ov1);
    }
}

extern "C" void kernel_launch(void* const* d_in, const int* in_sizes, int n_in, void* d_out, int out_size,
                              void* d_ws, size_t ws_size, hipStream_t stream) {
    const float* x = (const float*)d_in[0];
    const int* ei = (const int*)d_in[1];
    const float* ea = (const float*)d_in[2];
    const float* Wi = (const float*)d_in[3];
    const float* bi = (const float*)d_in[4];
    const float* Wq = (const float*)d_in[5];
    const float* bq = (const float*)d_in[6];
    const float* Wk = (const float*)d_in[7];
    const float* bk = (const float*)d_in[8];
    const float* Wv = (const float*)d_in[9];
    const float* bv = (const float*)d_in[10];
    const float* We = (const float*)d_in[11];
    const float* Wskip = (const float*)d_in[12];
    const float* bskip = (const float*)d_in[13];
    const float* Wbeta = (const float*)d_in[14];
    const float* lng = (const float*)d_in[15];
    const float* lnb = (const float*)d_in[16];

    const int* srcp = ei;
    const int* dstp = ei + NEDGES;

    char* p = (char*)d_ws;
    auto alloc = [&](size_t bytes) {
        void* r = (void*)p;
        p += (bytes + 255) & ~(size_t)255;
        return r;
    };
    unsigned* h32 = (unsigned*)alloc((size_t)NNODES * 64 * 4);
    unsigned* q32 = (unsigned*)alloc((size_t)NNODES * 64 * 4);
    unsigned* xr32 = (unsigned*)alloc((size_t)NNODES * 64 * 4);
    unsigned* kv = (unsigned*)alloc((size_t)NNODES * 64 * 4);
    unsigned short* Wit = (unsigned short*)alloc((size_t)DHID * DIN * 2);
    unsigned short* Wt3 = (unsigned short*)alloc((size_t)3 * 512 * DHID * 2);
    int* counts = (int*)alloc((size_t)NNODES * 4);
    int* row_ptr = (int*)alloc((size_t)(NNODES + 1) * 4);
    int2* esrc = (int2*)alloc((size_t)NEDGES * 8);
    int* partials = (int*)alloc(256 * 4);

    const int EB = (NEDGES + 255) / 256;
    const int NB = (NNODES + 255) / 256;
    const int GB = (NNODES + 127) / 128;       // 391
    const int WB = (NNODES * 64 + 255) / 256;  // 12500

    // weight prep
    prep_wi<<<(DHID * DIN + 255) / 256, 256, 0, stream>>>(Wi, Wit);
    prep_wqkvs<<<(3 * 512 * DHID + 255) / 256, 256, 0, stream>>>(Wq, Wk, Wv, Wskip, Wt3);

    // CSR by dst
    hipMemsetAsync(counts, 0, (size_t)NNODES * 4, stream);
    k_hist<<<EB, 256, 0, stream>>>(dstp, counts);
    k_scan_block<<<NB, 256, 0, stream>>>(counts, row_ptr + 1, partials, NNODES);
    k_scan_partials<<<1, 256, 0, stream>>>(partials, NB);
    k_apply<<<NB, 256, 0, stream>>>(partials, row_ptr, NNODES);
    hipMemsetAsync(counts, 0, (size_t)NNODES * 4, stream);
    k_scatter<<<EB, 256, 0, stream>>>(srcp, dstp, ea, row_ptr, counts, esrc);

    gemm_in<<<GB, 256, 0, stream>>>(x, Wit, bi, h32, NNODES);

    for (int l = 0; l < 3; ++l) {
        const size_t bo = (size_t)l * 128;
        gemm_qkvs<<<GB, 512, 0, stream>>>((const unsigned short*)h32, Wt3 + (size_t)l * 512 * DHID, bq + bo, bk + bo,
                                          bv + bo, bskip + bo, q32, kv, xr32, NNODES);
        node_attn_fuse<<<WB, 256, 0, stream>>>(q32, kv, esrc, We + bo, row_ptr, xr32, h32,
                                               Wbeta + (size_t)l * 384, lng + bo, lnb + bo, h32,
                                               (l == 2) ? (float*)d_out : nullptr);
    }
}

// Round 4
// 495.982 us; speedup vs baseline: 2.0394x; 1.0028x over previous
//
#include <hip/hip_runtime.h>
#include <math.h>

#define NNODES 50000
#define NEDGES 800000
#define DIN 256
#define DHID 128

typedef __attribute__((ext_vector_type(8))) short short8;
typedef __attribute__((ext_vector_type(4))) float f32x4;
typedef __attribute__((ext_vector_type(2))) float f32x2;

__device__ __forceinline__ unsigned short f2bf(float f) {
    unsigned u = __builtin_bit_cast(unsigned, f);
    u += 0x7fffu + ((u >> 16) & 1u);  // RNE
    return (unsigned short)(u >> 16);
}
__device__ __forceinline__ float bf2f(unsigned short s) {
    return __builtin_bit_cast(float, (unsigned)s << 16);
}
__device__ __forceinline__ unsigned packbf(float a, float b) {
    return (unsigned)f2bf(a) | ((unsigned)f2bf(b) << 16);
}

// ---------------- CSR build ----------------
__global__ __launch_bounds__(256) void k_hist(const int* __restrict__ dst, int* __restrict__ counts) {
    int e = blockIdx.x * 256 + threadIdx.x;
    if (e < NEDGES) atomicAdd(&counts[dst[e]], 1);
}

__global__ __launch_bounds__(256) void k_scan_block(const int* __restrict__ in, int* __restrict__ out,
                                                    int* __restrict__ partials, int n) {
    __shared__ int sh[256];
    int tid = threadIdx.x;
    int i = blockIdx.x * 256 + tid;
    int vv = (i < n) ? in[i] : 0;
    sh[tid] = vv;
    __syncthreads();
    for (int off = 1; off < 256; off <<= 1) {
        int t = (tid >= off) ? sh[tid - off] : 0;
        __syncthreads();
        sh[tid] += t;
        __syncthreads();
    }
    if (i < n) out[i] = sh[tid];
    if (tid == 255) partials[blockIdx.x] = sh[255];
}

__global__ __launch_bounds__(256) void k_scan_partials(int* __restrict__ partials, int nb) {
    __shared__ int sh[256];
    int tid = threadIdx.x;
    int vv = (tid < nb) ? partials[tid] : 0;
    sh[tid] = vv;
    __syncthreads();
    for (int off = 1; off < 256; off <<= 1) {
        int t = (tid >= off) ? sh[tid - off] : 0;
        __syncthreads();
        sh[tid] += t;
        __syncthreads();
    }
    if (tid < nb) partials[tid] = sh[tid];
}

__global__ __launch_bounds__(256) void k_apply(const int* __restrict__ partials, int* __restrict__ row_ptr, int n) {
    int i = blockIdx.x * 256 + threadIdx.x;
    if (i < n) {
        int add = blockIdx.x ? partials[blockIdx.x - 1] : 0;
        row_ptr[i + 1] += add;
    }
    if (i == 0) row_ptr[0] = 0;
}

// dst-sorted (src, ea) pairs
__global__ __launch_bounds__(256) void k_scatter(const int* __restrict__ src, const int* __restrict__ dst,
                                                 const float* __restrict__ ea, const int* __restrict__ row_ptr,
                                                 int* __restrict__ fill, int2* __restrict__ esrc) {
    int e = blockIdx.x * 256 + threadIdx.x;
    if (e < NEDGES) {
        int d = dst[e];
        int pos = row_ptr[d] + atomicAdd(&fill[d], 1);
        esrc[pos] = make_int2(src[e], __float_as_int(ea[e]));
    }
}

// ---------------- weight prep: transpose + bf16 cast ----------------
__global__ __launch_bounds__(256) void prep_wi(const float* __restrict__ Wi, unsigned short* __restrict__ Wit) {
    int idx = blockIdx.x * 256 + threadIdx.x;  // n*256 + k
    if (idx >= DHID * DIN) return;
    int n = idx >> 8, kk = idx & 255;
    Wit[idx] = f2bf(Wi[kk * DHID + n]);
}

// Wt3[l][512][128]: rows 0-127 Wq^T, 128-255 Wk^T, 256-383 Wv^T, 384-511 Wskip^T
__global__ __launch_bounds__(256) void prep_wqkvs(const float* __restrict__ Wq, const float* __restrict__ Wk,
                                                  const float* __restrict__ Wv, const float* __restrict__ Ws,
                                                  unsigned short* __restrict__ out) {
    int idx = blockIdx.x * 256 + threadIdx.x;
    if (idx >= 3 * 512 * DHID) return;
    int l = idx / (512 * DHID);
    int rem = idx - l * 512 * DHID;
    int r = rem >> 7;  // 0..511
    int kk = rem & 127;
    int sel = r >> 7, rl = r & 127;
    const float* srcm = sel == 0 ? Wq : sel == 1 ? Wk : sel == 2 ? Wv : Ws;
    out[idx] = f2bf(srcm[l * DHID * DHID + kk * DHID + rl]);
}

// ---------------- input projection: h[M,128](bf16) = x[M,256] @ Wi + bi ----------------
__global__ __launch_bounds__(256) void gemm_in(const float* __restrict__ A, const unsigned short* __restrict__ Wt,
                                               const float* __restrict__ bias, unsigned* __restrict__ h32, int M) {
    __shared__ short As[128 * 128];
    const int tid = threadIdx.x;
    const int lane = tid & 63;
    const int wid = tid >> 6;
    const int row0 = blockIdx.x * 128;
    const int wr = (wid & 1) * 64;
    const int wc = (wid >> 1) * 64;
    f32x4 acc[4][4] = {};
    const int srow = tid >> 1;
    const int sk = (tid & 1) * 64;
    const int grow = min(row0 + srow, M - 1);
    for (int kt = 0; kt < 2; ++kt) {
        const float* ap = A + (size_t)grow * DIN + kt * 128 + sk;
#pragma unroll
        for (int i = 0; i < 8; ++i) {
            float4 f0 = *(const float4*)(ap + i * 8);
            float4 f1 = *(const float4*)(ap + i * 8 + 4);
            short8 s;
            s[0] = f2bf(f0.x); s[1] = f2bf(f0.y); s[2] = f2bf(f0.z); s[3] = f2bf(f0.w);
            s[4] = f2bf(f1.x); s[5] = f2bf(f1.y); s[6] = f2bf(f1.z); s[7] = f2bf(f1.w);
            int g = (sk >> 3) + i;
            *(short8*)(&As[srow * 128 + ((g ^ (srow & 7)) << 3)]) = s;
        }
        __syncthreads();
#pragma unroll
        for (int ks = 0; ks < 4; ++ks) {
            short8 a[4], b[4];
#pragma unroll
            for (int m = 0; m < 4; ++m) {
                int r = wr + m * 16 + (lane & 15);
                int g = ks * 4 + (lane >> 4);
                a[m] = *(const short8*)(&As[r * 128 + ((g ^ (r & 7)) << 3)]);
            }
#pragma unroll
            for (int n = 0; n < 4; ++n) {
                int c = wc + n * 16 + (lane & 15);
                b[n] = *(const short8*)(Wt + (size_t)c * DIN + kt * 128 + ks * 32 + (lane >> 4) * 8);
            }
#pragma unroll
            for (int m = 0; m < 4; ++m)
#pragma unroll
                for (int n = 0; n < 4; ++n)
                    acc[m][n] = __builtin_amdgcn_mfma_f32_16x16x32_bf16(a[m], b[n], acc[m][n], 0, 0, 0);
        }
        __syncthreads();
    }
#pragma unroll
    for (int n = 0; n < 4; ++n) {
        int c = wc + n * 16 + (lane & 15);
        float bb = bias[c];
#pragma unroll
        for (int m = 0; m < 4; ++m)
#pragma unroll
            for (int j = 0; j < 4; ++j) {
                int r = row0 + wr + m * 16 + (lane >> 4) * 4 + j;
                float val = acc[m][n][j] + bb;
                float nb = __shfl_xor(val, 1);
                if (!(lane & 1) && r < M) h32[(size_t)r * 64 + (c >> 1)] = packbf(val, nb);
            }
    }
}

// ---------------- fused q/k/v/skip GEMM from bf16 h ----------------
// 8 waves: (wr, wc) 2x2 tile grid x sel: sel=0 computes q+skip, sel=1 computes k+v (packed fp8 kv)
__global__ __launch_bounds__(512) void gemm_qkvs(const unsigned short* __restrict__ A,
                                                 const unsigned short* __restrict__ Wt, const float* __restrict__ bq,
                                                 const float* __restrict__ bk, const float* __restrict__ bv,
                                                 const float* __restrict__ bs, unsigned* __restrict__ q32,
                                                 unsigned* __restrict__ kv, unsigned* __restrict__ xr32, int M) {
    __shared__ short As[128 * 128];
    const int tid = threadIdx.x;
    const int lane = tid & 63;
    const int wid = tid >> 6;
    const int row0 = blockIdx.x * 128;
    const int sel = wid >> 2;  // 0: q/skip, 1: k/v
    const int wr = (wid & 1) * 64;
    const int wc = ((wid >> 1) & 1) * 64;
    f32x4 acc0[4][4] = {}, acc1[4][4] = {};
    {
        const int srow = tid >> 2;
        const int sk = (tid & 3) * 32;
        const int grow = min(row0 + srow, M - 1);
        const unsigned short* ap = A + (size_t)grow * DHID + sk;
#pragma unroll
        for (int i = 0; i < 4; ++i) {
            short8 s = *(const short8*)(ap + i * 8);
            int g = (sk >> 3) + i;
            *(short8*)(&As[srow * 128 + ((g ^ (srow & 7)) << 3)]) = s;
        }
    }
    __syncthreads();
    const int b0base = sel ? 128 : 0;    // k : q
    const int b1base = sel ? 256 : 384;  // v : skip
#pragma unroll
    for (int ks = 0; ks < 4; ++ks) {
        short8 a[4], b0[4], b1[4];
#pragma unroll
        for (int m = 0; m < 4; ++m) {
            int r = wr + m * 16 + (lane & 15);
            int g = ks * 4 + (lane >> 4);
            a[m] = *(const short8*)(&As[r * 128 + ((g ^ (r & 7)) << 3)]);
        }
#pragma unroll
        for (int n = 0; n < 4; ++n) {
            int rb = wc + n * 16 + (lane & 15);
            b0[n] = *(const short8*)(Wt + (size_t)(b0base + rb) * DHID + ks * 32 + (lane >> 4) * 8);
            b1[n] = *(const short8*)(Wt + (size_t)(b1base + rb) * DHID + ks * 32 + (lane >> 4) * 8);
        }
#pragma unroll
        for (int m = 0; m < 4; ++m)
#pragma unroll
            for (int n = 0; n < 4; ++n) {
                acc0[m][n] = __builtin_amdgcn_mfma_f32_16x16x32_bf16(a[m], b0[n], acc0[m][n], 0, 0, 0);
                acc1[m][n] = __builtin_amdgcn_mfma_f32_16x16x32_bf16(a[m], b1[n], acc1[m][n], 0, 0, 0);
            }
    }
    const float* bias0 = sel ? bk : bq;
    const float* bias1 = sel ? bv : bs;
#pragma unroll
    for (int n = 0; n < 4; ++n) {
        int c = wc + n * 16 + (lane & 15);
        float bb0 = bias0[c];
        float bb1 = bias1[c];
#pragma unroll
        for (int m = 0; m < 4; ++m)
#pragma unroll
            for (int j = 0; j < 4; ++j) {
                int r = row0 + wr + m * 16 + (lane >> 4) * 4 + j;
                float v0 = acc0[m][n][j] + bb0;
                float v1 = acc1[m][n][j] + bb1;
                float n0 = __shfl_xor(v0, 1);
                float n1 = __shfl_xor(v1, 1);
                if (!(lane & 1) && r < M) {
                    if (sel == 0) {
                        q32[(size_t)r * 64 + (c >> 1)] = packbf(v0, n0);
                        xr32[(size_t)r * 64 + (c >> 1)] = packbf(v1, n1);
                    } else {
                        unsigned u = (unsigned)__builtin_amdgcn_cvt_pk_fp8_f32(v0, n0, 0, false);
                        u = (unsigned)__builtin_amdgcn_cvt_pk_fp8_f32(v1, n1, (int)u, true);
                        kv[(size_t)r * 64 + (c >> 1)] = u;
                    }
                }
            }
    }
}

// ---------------- per-node attention + beta-gate + GELU + LayerNorm (one wave per node) ----------------
// lane owns channels (2*lane, 2*lane+1); head = lane>>4. kv fp8-packed. houtb may alias res32 (same-wave RAW only).
__global__ __launch_bounds__(256) void node_attn_fuse(const unsigned* __restrict__ q32,
                                                      const unsigned* __restrict__ kv, const int2* __restrict__ esrc,
                                                      const float* __restrict__ We, const int* __restrict__ row_ptr,
                                                      const unsigned* __restrict__ xr32, const unsigned* res32,
                                                      const float* __restrict__ Wb, const float* __restrict__ lng,
                                                      const float* __restrict__ lnb, unsigned* houtb, float* houtf) {
    const int wid = (blockIdx.x * blockDim.x + threadIdx.x) >> 6;
    const int lane = threadIdx.x & 63;
    if (wid >= NNODES) return;
    const int base = row_ptr[wid], end = row_ptr[wid + 1];
    const int c0 = 2 * lane;
    const float2 wev = *(const float2*)(We + c0);
    const unsigned qw = q32[(size_t)wid * 64 + lane];
    const float q0 = bf2f((unsigned short)qw), q1 = bf2f((unsigned short)(qw >> 16));
    float m = -INFINITY, sden = 0.f, a0 = 0.f, a1 = 0.f;
    const float rsc = 0.17677669529663689f;  // 1/sqrt(32)
    for (int cb = base; cb < end; cb += 64) {
        int cnt = min(end - cb, 64);
        int s_l = 0;
        float a_l = 0.f;
        if (lane < cnt) {
            int2 sa = esrc[cb + lane];
            s_l = sa.x;
            a_l = __int_as_float(sa.y);
        }
        for (int j = 0; j < cnt; ++j) {
            int sN = __shfl(s_l, j);
            float av = __shfl(a_l, j);
            unsigned w = kv[(size_t)sN * 64 + lane];
            f32x2 kk = __builtin_amdgcn_cvt_pk_f32_fp8((int)w, false);
            f32x2 vv = __builtin_amdgcn_cvt_pk_f32_fp8((int)w, true);
            float kj0 = kk.x + av * wev.x, kj1 = kk.y + av * wev.y;
            float vj0 = vv.x + av * wev.x, vj1 = vv.y + av * wev.y;
            float p = q0 * kj0 + q1 * kj1;
            p += __shfl_xor(p, 1);
            p += __shfl_xor(p, 2);
            p += __shfl_xor(p, 4);
            p += __shfl_xor(p, 8);
            p *= rsc;
            float mn = fmaxf(m, p);
            float wgt = __expf(p - mn);
            float sc = __expf(m - mn);
            sden = sden * sc + wgt;
            a0 = a0 * sc + wgt * vj0;
            a1 = a1 * sc + wgt * vj1;
            m = mn;
        }
    }
    float o0 = a0 / (sden + 1e-16f), o1 = a1 / (sden + 1e-16f);
    const unsigned xw = xr32[(size_t)wid * 64 + lane];
    const float x0 = bf2f((unsigned short)xw), x1 = bf2f((unsigned short)(xw >> 16));
    const float2 w0 = *(const float2*)(Wb + c0);
    const float2 w1 = *(const float2*)(Wb + 128 + c0);
    const float2 w2 = *(const float2*)(Wb + 256 + c0);
    float bl = o0 * w0.x + o1 * w0.y + x0 * w1.x + x1 * w1.y + (o0 - x0) * w2.x + (o1 - x1) * w2.y;
#pragma unroll
    for (int off = 32; off; off >>= 1) bl += __shfl_xor(bl, off);
    float beta = 1.f / (1.f + __expf(-bl));
    float g0 = beta * x0 + (1.f - beta) * o0;
    float g1 = beta * x1 + (1.f - beta) * o1;
    g0 = 0.5f * g0 * (1.f + erff(g0 * 0.70710678118654752f));
    g1 = 0.5f * g1 * (1.f + erff(g1 * 0.70710678118654752f));
    const unsigned rw = res32[(size_t)wid * 64 + lane];
    float t0 = g0 + bf2f((unsigned short)rw);
    float t1 = g1 + bf2f((unsigned short)(rw >> 16));
    float su = t0 + t1, sq = t0 * t0 + t1 * t1;
#pragma unroll
    for (int off = 32; off; off >>= 1) {
        su += __shfl_xor(su, off);
        sq += __shfl_xor(sq, off);
    }
    float mu = su * (1.f / 128.f);
    float var = sq * (1.f / 128.f) - mu * mu;
    float inv = rsqrtf(var + 1e-5f);
    const float2 gv = *(const float2*)(lng + c0);
    const float2 bv2 = *(const float2*)(lnb + c0);
    float ov0 = (t0 - mu) * inv * gv.x + bv2.x;
    float ov1 = (t1 - mu) * inv * gv.y + bv2.y;
    if (houtf) {
        *(float2*)(houtf + (size_t)wid * 128 + c0) = make_float2(ov0, ov1);
    } else {
        houtb[(size_t)wid * 64 + lane] = packbf(ov0, ov1);
    }
}

extern "C" void kernel_launch(void* const* d_in, const int* in_sizes, int n_in, void* d_out, int out_size,
                              void* d_ws, size_t ws_size, hipStream_t stream) {
    const float* x = (const float*)d_in[0];
    const int* ei = (const int*)d_in[1];
    const float* ea = (const float*)d_in[2];
    const float* Wi = (const float*)d_in[3];
    const float* bi = (const float*)d_in[4];
    const float* Wq = (const float*)d_in[5];
    const float* bq = (const float*)d_in[6];
    const float* Wk = (const float*)d_in[7];
    const float* bk = (const float*)d_in[8];
    const float* Wv = (const float*)d_in[9];
    const float* bv = (const float*)d_in[10];
    const float* We = (const float*)d_in[11];
    const float* Wskip = (const float*)d_in[12];
    const float* bskip = (const float*)d_in[13];
    const float* Wbeta = (const float*)d_in[14];
    const float* lng = (const float*)d_in[15];
    const float* lnb = (const float*)d_in[16];

    const int* srcp = ei;
    const int* dstp = ei + NEDGES;

    char* p = (char*)d_ws;
    auto alloc = [&](size_t bytes) {
        void* r = (void*)p;
        p += (bytes + 255) & ~(size_t)255;
        return r;
    };
    unsigned* h32 = (unsigned*)alloc((size_t)NNODES * 64 * 4);
    unsigned* q32 = (unsigned*)alloc((size_t)NNODES * 64 * 4);
    unsigned* xr32 = (unsigned*)alloc((size_t)NNODES * 64 * 4);
    unsigned* kv = (unsigned*)alloc((size_t)NNODES * 64 * 4);
    unsigned short* Wit = (unsigned short*)alloc((size_t)DHID * DIN * 2);
    unsigned short* Wt3 = (unsigned short*)alloc((size_t)3 * 512 * DHID * 2);
    int* counts = (int*)alloc((size_t)NNODES * 4);
    int* row_ptr = (int*)alloc((size_t)(NNODES + 1) * 4);
    int2* esrc = (int2*)alloc((size_t)NEDGES * 8);
    int* partials = (int*)alloc(256 * 4);

    const int EB = (NEDGES + 255) / 256;
    const int NB = (NNODES + 255) / 256;
    const int GB = (NNODES + 127) / 128;       // 391
    const int WB = (NNODES * 64 + 255) / 256;  // 12500

    // weight prep
    prep_wi<<<(DHID * DIN + 255) / 256, 256, 0, stream>>>(Wi, Wit);
    prep_wqkvs<<<(3 * 512 * DHID + 255) / 256, 256, 0, stream>>>(Wq, Wk, Wv, Wskip, Wt3);

    // CSR by dst
    hipMemsetAsync(counts, 0, (size_t)NNODES * 4, stream);
    k_hist<<<EB, 256, 0, stream>>>(dstp, counts);
    k_scan_block<<<NB, 256, 0, stream>>>(counts, row_ptr + 1, partials, NNODES);
    k_scan_partials<<<1, 256, 0, stream>>>(partials, NB);
    k_apply<<<NB, 256, 0, stream>>>(partials, row_ptr, NNODES);
    hipMemsetAsync(counts, 0, (size_t)NNODES * 4, stream);
    k_scatter<<<EB, 256, 0, stream>>>(srcp, dstp, ea, row_ptr, counts, esrc);

    gemm_in<<<GB, 256, 0, stream>>>(x, Wit, bi, h32, NNODES);

    for (int l = 0; l < 3; ++l) {
        const size_t bo = (size_t)l * 128;
        gemm_qkvs<<<GB, 512, 0, stream>>>((const unsigned short*)h32, Wt3 + (size_t)l * 512 * DHID, bq + bo, bk + bo,
                                          bv + bo, bskip + bo, q32, kv, xr32, NNODES);
        node_attn_fuse<<<WB, 256, 0, stream>>>(q32, kv, esrc, We + bo, row_ptr, xr32, h32,
                                               Wbeta + (size_t)l * 384, lng + bo, lnb + bo, h32,
                                               (l == 2) ? (float*)d_out : nullptr);
    }
}

// Round 5
// 489.601 us; speedup vs baseline: 2.0659x; 1.0130x over previous
//
#include <hip/hip_runtime.h>
#include <math.h>

#define NNODES 50000
#define NEDGES 800000
#define DIN 256
#define DHID 128

typedef __attribute__((ext_vector_type(8))) short short8;
typedef __attribute__((ext_vector_type(4))) float f32x4;
typedef __attribute__((ext_vector_type(2))) float f32x2;

__device__ __forceinline__ unsigned short f2bf(float f) {
    unsigned u = __builtin_bit_cast(unsigned, f);
    u += 0x7fffu + ((u >> 16) & 1u);  // RNE
    return (unsigned short)(u >> 16);
}
__device__ __forceinline__ float bf2f(unsigned short s) {
    return __builtin_bit_cast(float, (unsigned)s << 16);
}
__device__ __forceinline__ unsigned packbf(float a, float b) {
    return (unsigned)f2bf(a) | ((unsigned)f2bf(b) << 16);
}

// ---------------- CSR build ----------------
__global__ __launch_bounds__(256) void k_hist(const int* __restrict__ dst, int* __restrict__ counts) {
    int e = blockIdx.x * 256 + threadIdx.x;
    if (e < NEDGES) atomicAdd(&counts[dst[e]], 1);
}

__global__ __launch_bounds__(256) void k_scan_block(const int* __restrict__ in, int* __restrict__ out,
                                                    int* __restrict__ partials, int n) {
    __shared__ int sh[256];
    int tid = threadIdx.x;
    int i = blockIdx.x * 256 + tid;
    int vv = (i < n) ? in[i] : 0;
    sh[tid] = vv;
    __syncthreads();
    for (int off = 1; off < 256; off <<= 1) {
        int t = (tid >= off) ? sh[tid - off] : 0;
        __syncthreads();
        sh[tid] += t;
        __syncthreads();
    }
    if (i < n) out[i] = sh[tid];
    if (tid == 255) partials[blockIdx.x] = sh[255];
}

__global__ __launch_bounds__(256) void k_scan_partials(int* __restrict__ partials, int nb) {
    __shared__ int sh[256];
    int tid = threadIdx.x;
    int vv = (tid < nb) ? partials[tid] : 0;
    sh[tid] = vv;
    __syncthreads();
    for (int off = 1; off < 256; off <<= 1) {
        int t = (tid >= off) ? sh[tid - off] : 0;
        __syncthreads();
        sh[tid] += t;
        __syncthreads();
    }
    if (tid < nb) partials[tid] = sh[tid];
}

__global__ __launch_bounds__(256) void k_apply(const int* __restrict__ partials, int* __restrict__ row_ptr, int n) {
    int i = blockIdx.x * 256 + threadIdx.x;
    if (i < n) {
        int add = blockIdx.x ? partials[blockIdx.x - 1] : 0;
        row_ptr[i + 1] += add;
    }
    if (i == 0) row_ptr[0] = 0;
}

// dst-sorted (src, ea) pairs
__global__ __launch_bounds__(256) void k_scatter(const int* __restrict__ src, const int* __restrict__ dst,
                                                 const float* __restrict__ ea, const int* __restrict__ row_ptr,
                                                 int* __restrict__ fill, int2* __restrict__ esrc) {
    int e = blockIdx.x * 256 + threadIdx.x;
    if (e < NEDGES) {
        int d = dst[e];
        int pos = row_ptr[d] + atomicAdd(&fill[d], 1);
        esrc[pos] = make_int2(src[e], __float_as_int(ea[e]));
    }
}

// ---------------- weight prep: transpose + bf16 cast ----------------
__global__ __launch_bounds__(256) void prep_wi(const float* __restrict__ Wi, unsigned short* __restrict__ Wit) {
    int idx = blockIdx.x * 256 + threadIdx.x;  // n*256 + k
    if (idx >= DHID * DIN) return;
    int n = idx >> 8, kk = idx & 255;
    Wit[idx] = f2bf(Wi[kk * DHID + n]);
}

// Wt3[l][512][128]: rows 0-127 Wq^T, 128-255 Wk^T, 256-383 Wv^T, 384-511 Wskip^T
__global__ __launch_bounds__(256) void prep_wqkvs(const float* __restrict__ Wq, const float* __restrict__ Wk,
                                                  const float* __restrict__ Wv, const float* __restrict__ Ws,
                                                  unsigned short* __restrict__ out) {
    int idx = blockIdx.x * 256 + threadIdx.x;
    if (idx >= 3 * 512 * DHID) return;
    int l = idx / (512 * DHID);
    int rem = idx - l * 512 * DHID;
    int r = rem >> 7;  // 0..511
    int kk = rem & 127;
    int sel = r >> 7, rl = r & 127;
    const float* srcm = sel == 0 ? Wq : sel == 1 ? Wk : sel == 2 ? Wv : Ws;
    out[idx] = f2bf(srcm[l * DHID * DHID + kk * DHID + rl]);
}

// ---------------- input projection: h[M,128](bf16) = x[M,256] @ Wi + bi ----------------
__global__ __launch_bounds__(256) void gemm_in(const float* __restrict__ A, const unsigned short* __restrict__ Wt,
                                               const float* __restrict__ bias, unsigned* __restrict__ h32, int M) {
    __shared__ short As[128 * 128];
    const int tid = threadIdx.x;
    const int lane = tid & 63;
    const int wid = tid >> 6;
    const int row0 = blockIdx.x * 128;
    const int wr = (wid & 1) * 64;
    const int wc = (wid >> 1) * 64;
    f32x4 acc[4][4] = {};
    const int srow = tid >> 1;
    const int sk = (tid & 1) * 64;
    const int grow = min(row0 + srow, M - 1);
    for (int kt = 0; kt < 2; ++kt) {
        const float* ap = A + (size_t)grow * DIN + kt * 128 + sk;
#pragma unroll
        for (int i = 0; i < 8; ++i) {
            float4 f0 = *(const float4*)(ap + i * 8);
            float4 f1 = *(const float4*)(ap + i * 8 + 4);
            short8 s;
            s[0] = f2bf(f0.x); s[1] = f2bf(f0.y); s[2] = f2bf(f0.z); s[3] = f2bf(f0.w);
            s[4] = f2bf(f1.x); s[5] = f2bf(f1.y); s[6] = f2bf(f1.z); s[7] = f2bf(f1.w);
            int g = (sk >> 3) + i;
            *(short8*)(&As[srow * 128 + ((g ^ (srow & 7)) << 3)]) = s;
        }
        __syncthreads();
#pragma unroll
        for (int ks = 0; ks < 4; ++ks) {
            short8 a[4], b[4];
#pragma unroll
            for (int m = 0; m < 4; ++m) {
                int r = wr + m * 16 + (lane & 15);
                int g = ks * 4 + (lane >> 4);
                a[m] = *(const short8*)(&As[r * 128 + ((g ^ (r & 7)) << 3)]);
            }
#pragma unroll
            for (int n = 0; n < 4; ++n) {
                int c = wc + n * 16 + (lane & 15);
                b[n] = *(const short8*)(Wt + (size_t)c * DIN + kt * 128 + ks * 32 + (lane >> 4) * 8);
            }
#pragma unroll
            for (int m = 0; m < 4; ++m)
#pragma unroll
                for (int n = 0; n < 4; ++n)
                    acc[m][n] = __builtin_amdgcn_mfma_f32_16x16x32_bf16(a[m], b[n], acc[m][n], 0, 0, 0);
        }
        __syncthreads();
    }
#pragma unroll
    for (int n = 0; n < 4; ++n) {
        int c = wc + n * 16 + (lane & 15);
        float bb = bias[c];
#pragma unroll
        for (int m = 0; m < 4; ++m)
#pragma unroll
            for (int j = 0; j < 4; ++j) {
                int r = row0 + wr + m * 16 + (lane >> 4) * 4 + j;
                float val = acc[m][n][j] + bb;
                float nb = __shfl_xor(val, 1);
                if (!(lane & 1) && r < M) h32[(size_t)r * 64 + (c >> 1)] = packbf(val, nb);
            }
    }
}

// ---------------- fused q/k/v/skip GEMM from bf16 h ----------------
// 8 waves: (wr, wc) 2x2 tile grid x sel: sel=0 computes q+skip, sel=1 computes k+v (packed fp8 kv)
__global__ __launch_bounds__(512) void gemm_qkvs(const unsigned short* __restrict__ A,
                                                 const unsigned short* __restrict__ Wt, const float* __restrict__ bq,
                                                 const float* __restrict__ bk, const float* __restrict__ bv,
                                                 const float* __restrict__ bs, unsigned* __restrict__ q32,
                                                 unsigned* __restrict__ kv, unsigned* __restrict__ xr32, int M) {
    __shared__ short As[128 * 128];
    const int tid = threadIdx.x;
    const int lane = tid & 63;
    const int wid = tid >> 6;
    const int row0 = blockIdx.x * 128;
    const int sel = wid >> 2;  // 0: q/skip, 1: k/v
    const int wr = (wid & 1) * 64;
    const int wc = ((wid >> 1) & 1) * 64;
    f32x4 acc0[4][4] = {}, acc1[4][4] = {};
    {
        const int srow = tid >> 2;
        const int sk = (tid & 3) * 32;
        const int grow = min(row0 + srow, M - 1);
        const unsigned short* ap = A + (size_t)grow * DHID + sk;
#pragma unroll
        for (int i = 0; i < 4; ++i) {
            short8 s = *(const short8*)(ap + i * 8);
            int g = (sk >> 3) + i;
            *(short8*)(&As[srow * 128 + ((g ^ (srow & 7)) << 3)]) = s;
        }
    }
    __syncthreads();
    const int b0base = sel ? 128 : 0;    // k : q
    const int b1base = sel ? 256 : 384;  // v : skip
#pragma unroll
    for (int ks = 0; ks < 4; ++ks) {
        short8 a[4], b0[4], b1[4];
#pragma unroll
        for (int m = 0; m < 4; ++m) {
            int r = wr + m * 16 + (lane & 15);
            int g = ks * 4 + (lane >> 4);
            a[m] = *(const short8*)(&As[r * 128 + ((g ^ (r & 7)) << 3)]);
        }
#pragma unroll
        for (int n = 0; n < 4; ++n) {
            int rb = wc + n * 16 + (lane & 15);
            b0[n] = *(const short8*)(Wt + (size_t)(b0base + rb) * DHID + ks * 32 + (lane >> 4) * 8);
            b1[n] = *(const short8*)(Wt + (size_t)(b1base + rb) * DHID + ks * 32 + (lane >> 4) * 8);
        }
#pragma unroll
        for (int m = 0; m < 4; ++m)
#pragma unroll
            for (int n = 0; n < 4; ++n) {
                acc0[m][n] = __builtin_amdgcn_mfma_f32_16x16x32_bf16(a[m], b0[n], acc0[m][n], 0, 0, 0);
                acc1[m][n] = __builtin_amdgcn_mfma_f32_16x16x32_bf16(a[m], b1[n], acc1[m][n], 0, 0, 0);
            }
    }
    const float* bias0 = sel ? bk : bq;
    const float* bias1 = sel ? bv : bs;
#pragma unroll
    for (int n = 0; n < 4; ++n) {
        int c = wc + n * 16 + (lane & 15);
        float bb0 = bias0[c];
        float bb1 = bias1[c];
#pragma unroll
        for (int m = 0; m < 4; ++m)
#pragma unroll
            for (int j = 0; j < 4; ++j) {
                int r = row0 + wr + m * 16 + (lane >> 4) * 4 + j;
                float v0 = acc0[m][n][j] + bb0;
                float v1 = acc1[m][n][j] + bb1;
                float n0 = __shfl_xor(v0, 1);
                float n1 = __shfl_xor(v1, 1);
                if (!(lane & 1) && r < M) {
                    if (sel == 0) {
                        q32[(size_t)r * 64 + (c >> 1)] = packbf(v0, n0);
                        xr32[(size_t)r * 64 + (c >> 1)] = packbf(v1, n1);
                    } else {
                        unsigned u = (unsigned)__builtin_amdgcn_cvt_pk_fp8_f32(v0, n0, 0, false);
                        u = (unsigned)__builtin_amdgcn_cvt_pk_fp8_f32(v1, n1, (int)u, true);
                        kv[(size_t)r * 64 + (c >> 1)] = u;
                    }
                }
            }
    }
}

// ---------------- per-node attention + beta-gate + GELU + LayerNorm (one wave per node) ----------------
// lane owns channels (2*lane, 2*lane+1); head = lane>>4. kv fp8-packed. houtb may alias res32 (same-wave RAW only).
__global__ __launch_bounds__(256) void node_attn_fuse(const unsigned* __restrict__ q32,
                                                      const unsigned* __restrict__ kv, const int2* __restrict__ esrc,
                                                      const float* __restrict__ We, const int* __restrict__ row_ptr,
                                                      const unsigned* __restrict__ xr32, const unsigned* res32,
                                                      const float* __restrict__ Wb, const float* __restrict__ lng,
                                                      const float* __restrict__ lnb, unsigned* houtb, float* houtf) {
    const int wid = (blockIdx.x * blockDim.x + threadIdx.x) >> 6;
    const int lane = threadIdx.x & 63;
    if (wid >= NNODES) return;
    const int base = row_ptr[wid], end = row_ptr[wid + 1];
    const int c0 = 2 * lane;
    const float2 wev = *(const float2*)(We + c0);
    const unsigned qw = q32[(size_t)wid * 64 + lane];
    const float q0 = bf2f((unsigned short)qw), q1 = bf2f((unsigned short)(qw >> 16));
    float m = -INFINITY, sden = 0.f, a0 = 0.f, a1 = 0.f;
    const float rsc = 0.17677669529663689f;  // 1/sqrt(32)
    for (int cb = base; cb < end; cb += 64) {
        int cnt = min(end - cb, 64);
        int s_l = 0;
        float a_l = 0.f;
        if (lane < cnt) {
            int2 sa = esrc[cb + lane];
            s_l = sa.x;
            a_l = __int_as_float(sa.y);
        }
        for (int j = 0; j < cnt; ++j) {
            int sN = __shfl(s_l, j);
            float av = __shfl(a_l, j);
            unsigned w = kv[(size_t)sN * 64 + lane];
            f32x2 kk = __builtin_amdgcn_cvt_pk_f32_fp8((int)w, false);
            f32x2 vv = __builtin_amdgcn_cvt_pk_f32_fp8((int)w, true);
            float kj0 = kk.x + av * wev.x, kj1 = kk.y + av * wev.y;
            float vj0 = vv.x + av * wev.x, vj1 = vv.y + av * wev.y;
            float p = q0 * kj0 + q1 * kj1;
            p += __shfl_xor(p, 1);
            p += __shfl_xor(p, 2);
            p += __shfl_xor(p, 4);
            p += __shfl_xor(p, 8);
            p *= rsc;
            float mn = fmaxf(m, p);
            float wgt = __expf(p - mn);
            float sc = __expf(m - mn);
            sden = sden * sc + wgt;
            a0 = a0 * sc + wgt * vj0;
            a1 = a1 * sc + wgt * vj1;
            m = mn;
        }
    }
    float o0 = a0 / (sden + 1e-16f), o1 = a1 / (sden + 1e-16f);
    const unsigned xw = xr32[(size_t)wid * 64 + lane];
    const float x0 = bf2f((unsigned short)xw), x1 = bf2f((unsigned short)(xw >> 16));
    const float2 w0 = *(const float2*)(Wb + c0);
    const float2 w1 = *(const float2*)(Wb + 128 + c0);
    const float2 w2 = *(const float2*)(Wb + 256 + c0);
    float bl = o0 * w0.x + o1 * w0.y + x0 * w1.x + x1 * w1.y + (o0 - x0) * w2.x + (o1 - x1) * w2.y;
#pragma unroll
    for (int off = 32; off; off >>= 1) bl += __shfl_xor(bl, off);
    float beta = 1.f / (1.f + __expf(-bl));
    float g0 = beta * x0 + (1.f - beta) * o0;
    float g1 = beta * x1 + (1.f - beta) * o1;
    g0 = 0.5f * g0 * (1.f + erff(g0 * 0.70710678118654752f));
    g1 = 0.5f * g1 * (1.f + erff(g1 * 0.70710678118654752f));
    const unsigned rw = res32[(size_t)wid * 64 + lane];
    float t0 = g0 + bf2f((unsigned short)rw);
    float t1 = g1 + bf2f((unsigned short)(rw >> 16));
    float su = t0 + t1, sq = t0 * t0 + t1 * t1;
#pragma unroll
    for (int off = 32; off; off >>= 1) {
        su += __shfl_xor(su, off);
        sq += __shfl_xor(sq, off);
    }
    float mu = su * (1.f / 128.f);
    float var = sq * (1.f / 128.f) - mu * mu;
    float inv = rsqrtf(var + 1e-5f);
    const float2 gv = *(const float2*)(lng + c0);
    const float2 bv2 = *(const float2*)(lnb + c0);
    float ov0 = (t0 - mu) * inv * gv.x + bv2.x;
    float ov1 = (t1 - mu) * inv * gv.y + bv2.y;
    if (houtf) {
        *(float2*)(houtf + (size_t)wid * 128 + c0) = make_float2(ov0, ov1);
    } else {
        houtb[(size_t)wid * 64 + lane] = packbf(ov0, ov1);
    }
}

extern "C" void kernel_launch(void* const* d_in, const int* in_sizes, int n_in, void* d_out, int out_size,
                              void* d_ws, size_t ws_size, hipStream_t stream) {
    const float* x = (const float*)d_in[0];
    const int* ei = (const int*)d_in[1];
    const float* ea = (const float*)d_in[2];
    const float* Wi = (const float*)d_in[3];
    const float* bi = (const float*)d_in[4];
    const float* Wq = (const float*)d_in[5];
    const float* bq = (const float*)d_in[6];
    const float* Wk = (const float*)d_in[7];
    const float* bk = (const float*)d_in[8];
    const float* Wv = (const float*)d_in[9];
    const float* bv = (const float*)d_in[10];
    const float* We = (const float*)d_in[11];
    const float* Wskip = (const float*)d_in[12];
    const float* bskip = (const float*)d_in[13];
    const float* Wbeta = (const float*)d_in[14];
    const float* lng = (const float*)d_in[15];
    const float* lnb = (const float*)d_in[16];

    const int* srcp = ei;
    const int* dstp = ei + NEDGES;

    char* p = (char*)d_ws;
    auto alloc = [&](size_t bytes) {
        void* r = (void*)p;
        p += (bytes + 255) & ~(size_t)255;
        return r;
    };
    unsigned* h32 = (unsigned*)alloc((size_t)NNODES * 64 * 4);
    unsigned* q32 = (unsigned*)alloc((size_t)NNODES * 64 * 4);
    unsigned* xr32 = (unsigned*)alloc((size_t)NNODES * 64 * 4);
    unsigned* kv = (unsigned*)alloc((size_t)NNODES * 64 * 4);
    unsigned short* Wit = (unsigned short*)alloc((size_t)DHID * DIN * 2);
    unsigned short* Wt3 = (unsigned short*)alloc((size_t)3 * 512 * DHID * 2);
    int* counts = (int*)alloc((size_t)NNODES * 4);
    int* row_ptr = (int*)alloc((size_t)(NNODES + 1) * 4);
    int2* esrc = (int2*)alloc((size_t)NEDGES * 8);
    int* partials = (int*)alloc(256 * 4);

    const int EB = (NEDGES + 255) / 256;
    const int NB = (NNODES + 255) / 256;
    const int GB = (NNODES + 127) / 128;       // 391
    const int WB = (NNODES * 64 + 255) / 256;  // 12500

    // weight prep
    prep_wi<<<(DHID * DIN + 255) / 256, 256, 0, stream>>>(Wi, Wit);
    prep_wqkvs<<<(3 * 512 * DHID + 255) / 256, 256, 0, stream>>>(Wq, Wk, Wv, Wskip, Wt3);

    // CSR by dst
    hipMemsetAsync(counts, 0, (size_t)NNODES * 4, stream);
    k_hist<<<EB, 256, 0, stream>>>(dstp, counts);
    k_scan_block<<<NB, 256, 0, stream>>>(counts, row_ptr + 1, partials, NNODES);
    k_scan_partials<<<1, 256, 0, stream>>>(partials, NB);
    k_apply<<<NB, 256, 0, stream>>>(partials, row_ptr, NNODES);
    hipMemsetAsync(counts, 0, (size_t)NNODES * 4, stream);
    k_scatter<<<EB, 256, 0, stream>>>(srcp, dstp, ea, row_ptr, counts, esrc);

    gemm_in<<<GB, 256, 0, stream>>>(x, Wit, bi, h32, NNODES);

    for (int l = 0; l < 3; ++l) {
        const size_t bo = (size_t)l * 128;
        gemm_qkvs<<<GB, 512, 0, stream>>>((const unsigned short*)h32, Wt3 + (size_t)l * 512 * DHID, bq + bo, bk + bo,
                                          bv + bo, bskip + bo, q32, kv, xr32, NNODES);
        node_attn_fuse<<<WB, 256, 0, stream>>>(q32, kv, esrc, We + bo, row_ptr, xr32, h32,
                                               Wbeta + (size_t)l * 384, lng + bo, lnb + bo, h32,
                                               (l == 2) ? (float*)d_out : nullptr);
    }
}

// Round 6
// 487.653 us; speedup vs baseline: 2.0742x; 1.0040x over previous
//
#include <hip/hip_runtime.h>
#include <math.h>

#define NNODES 50000
#define NEDGES 800000
#define DIN 256
#define DHID 128

typedef __attribute__((ext_vector_type(8))) short short8;
typedef __attribute__((ext_vector_type(4))) float f32x4;
typedef __attribute__((ext_vector_type(2))) float f32x2;

__device__ __forceinline__ unsigned short f2bf(float f) {
    unsigned u = __builtin_bit_cast(unsigned, f);
    u += 0x7fffu + ((u >> 16) & 1u);  // RNE
    return (unsigned short)(u >> 16);
}
__device__ __forceinline__ float bf2f(unsigned short s) {
    return __builtin_bit_cast(float, (unsigned)s << 16);
}
__device__ __forceinline__ unsigned packbf(float a, float b) {
    return (unsigned)f2bf(a) | ((unsigned)f2bf(b) << 16);
}

// ---------------- CSR build ----------------
__global__ __launch_bounds__(256) void k_hist(const int* __restrict__ dst, int* __restrict__ counts) {
    int e = blockIdx.x * 256 + threadIdx.x;
    if (e < NEDGES) atomicAdd(&counts[dst[e]], 1);
}

__global__ __launch_bounds__(256) void k_scan_block(const int* __restrict__ in, int* __restrict__ out,
                                                    int* __restrict__ partials, int n) {
    __shared__ int sh[256];
    int tid = threadIdx.x;
    int i = blockIdx.x * 256 + tid;
    int vv = (i < n) ? in[i] : 0;
    sh[tid] = vv;
    __syncthreads();
    for (int off = 1; off < 256; off <<= 1) {
        int t = (tid >= off) ? sh[tid - off] : 0;
        __syncthreads();
        sh[tid] += t;
        __syncthreads();
    }
    if (i < n) out[i] = sh[tid];
    if (tid == 255) partials[blockIdx.x] = sh[255];
}

__global__ __launch_bounds__(256) void k_scan_partials(int* __restrict__ partials, int nb) {
    __shared__ int sh[256];
    int tid = threadIdx.x;
    int vv = (tid < nb) ? partials[tid] : 0;
    sh[tid] = vv;
    __syncthreads();
    for (int off = 1; off < 256; off <<= 1) {
        int t = (tid >= off) ? sh[tid - off] : 0;
        __syncthreads();
        sh[tid] += t;
        __syncthreads();
    }
    if (tid < nb) partials[tid] = sh[tid];
}

__global__ __launch_bounds__(256) void k_apply(const int* __restrict__ partials, int* __restrict__ row_ptr, int n) {
    int i = blockIdx.x * 256 + threadIdx.x;
    if (i < n) {
        int add = blockIdx.x ? partials[blockIdx.x - 1] : 0;
        row_ptr[i + 1] += add;
    }
    if (i == 0) row_ptr[0] = 0;
}

// dst-sorted (src, ea) pairs
__global__ __launch_bounds__(256) void k_scatter(const int* __restrict__ src, const int* __restrict__ dst,
                                                 const float* __restrict__ ea, const int* __restrict__ row_ptr,
                                                 int* __restrict__ fill, int2* __restrict__ esrc) {
    int e = blockIdx.x * 256 + threadIdx.x;
    if (e < NEDGES) {
        int d = dst[e];
        int pos = row_ptr[d] + atomicAdd(&fill[d], 1);
        esrc[pos] = make_int2(src[e], __float_as_int(ea[e]));
    }
}

// ---------------- weight prep: transpose + bf16 cast ----------------
__global__ __launch_bounds__(256) void prep_wi(const float* __restrict__ Wi, unsigned short* __restrict__ Wit) {
    int idx = blockIdx.x * 256 + threadIdx.x;  // n*256 + k
    if (idx >= DHID * DIN) return;
    int n = idx >> 8, kk = idx & 255;
    Wit[idx] = f2bf(Wi[kk * DHID + n]);
}

// Wt3[l][512][128]: rows 0-127 Wq^T, 128-255 Wk^T, 256-383 Wv^T, 384-511 Wskip^T
__global__ __launch_bounds__(256) void prep_wqkvs(const float* __restrict__ Wq, const float* __restrict__ Wk,
                                                  const float* __restrict__ Wv, const float* __restrict__ Ws,
                                                  unsigned short* __restrict__ out) {
    int idx = blockIdx.x * 256 + threadIdx.x;
    if (idx >= 3 * 512 * DHID) return;
    int l = idx / (512 * DHID);
    int rem = idx - l * 512 * DHID;
    int r = rem >> 7;  // 0..511
    int kk = rem & 127;
    int sel = r >> 7, rl = r & 127;
    const float* srcm = sel == 0 ? Wq : sel == 1 ? Wk : sel == 2 ? Wv : Ws;
    out[idx] = f2bf(srcm[l * DHID * DHID + kk * DHID + rl]);
}

// ---------------- input projection: h[M,128](bf16) = x[M,256] @ Wi + bi ----------------
__global__ __launch_bounds__(256) void gemm_in(const float* __restrict__ A, const unsigned short* __restrict__ Wt,
                                               const float* __restrict__ bias, unsigned* __restrict__ h32, int M) {
    __shared__ short As[128 * 128];
    const int tid = threadIdx.x;
    const int lane = tid & 63;
    const int wid = tid >> 6;
    const int row0 = blockIdx.x * 128;
    const int wr = (wid & 1) * 64;
    const int wc = (wid >> 1) * 64;
    f32x4 acc[4][4] = {};
    const int srow = tid >> 1;
    const int sk = (tid & 1) * 64;
    const int grow = min(row0 + srow, M - 1);
    for (int kt = 0; kt < 2; ++kt) {
        const float* ap = A + (size_t)grow * DIN + kt * 128 + sk;
#pragma unroll
        for (int i = 0; i < 8; ++i) {
            float4 f0 = *(const float4*)(ap + i * 8);
            float4 f1 = *(const float4*)(ap + i * 8 + 4);
            short8 s;
            s[0] = f2bf(f0.x); s[1] = f2bf(f0.y); s[2] = f2bf(f0.z); s[3] = f2bf(f0.w);
            s[4] = f2bf(f1.x); s[5] = f2bf(f1.y); s[6] = f2bf(f1.z); s[7] = f2bf(f1.w);
            int g = (sk >> 3) + i;
            *(short8*)(&As[srow * 128 + ((g ^ (srow & 7)) << 3)]) = s;
        }
        __syncthreads();
#pragma unroll
        for (int ks = 0; ks < 4; ++ks) {
            short8 a[4], b[4];
#pragma unroll
            for (int m = 0; m < 4; ++m) {
                int r = wr + m * 16 + (lane & 15);
                int g = ks * 4 + (lane >> 4);
                a[m] = *(const short8*)(&As[r * 128 + ((g ^ (r & 7)) << 3)]);
            }
#pragma unroll
            for (int n = 0; n < 4; ++n) {
                int c = wc + n * 16 + (lane & 15);
                b[n] = *(const short8*)(Wt + (size_t)c * DIN + kt * 128 + ks * 32 + (lane >> 4) * 8);
            }
#pragma unroll
            for (int m = 0; m < 4; ++m)
#pragma unroll
                for (int n = 0; n < 4; ++n)
                    acc[m][n] = __builtin_amdgcn_mfma_f32_16x16x32_bf16(a[m], b[n], acc[m][n], 0, 0, 0);
        }
        __syncthreads();
    }
#pragma unroll
    for (int n = 0; n < 4; ++n) {
        int c = wc + n * 16 + (lane & 15);
        float bb = bias[c];
#pragma unroll
        for (int m = 0; m < 4; ++m)
#pragma unroll
            for (int j = 0; j < 4; ++j) {
                int r = row0 + wr + m * 16 + (lane >> 4) * 4 + j;
                float val = acc[m][n][j] + bb;
                float nb = __shfl_xor(val, 1);
                if (!(lane & 1) && r < M) h32[(size_t)r * 64 + (c >> 1)] = packbf(val, nb);
            }
    }
}

// ---------------- fused q/k/v/skip GEMM from bf16 h ----------------
// 8 waves: (wr, wc) 2x2 tile grid x sel: sel=0 computes q+skip, sel=1 computes k+v (packed fp8 kv)
__global__ __launch_bounds__(512) void gemm_qkvs(const unsigned short* __restrict__ A,
                                                 const unsigned short* __restrict__ Wt, const float* __restrict__ bq,
                                                 const float* __restrict__ bk, const float* __restrict__ bv,
                                                 const float* __restrict__ bs, unsigned* __restrict__ q32,
                                                 unsigned* __restrict__ kv, unsigned* __restrict__ xr32, int M) {
    __shared__ short As[128 * 128];
    const int tid = threadIdx.x;
    const int lane = tid & 63;
    const int wid = tid >> 6;
    const int row0 = blockIdx.x * 128;
    const int sel = wid >> 2;  // 0: q/skip, 1: k/v
    const int wr = (wid & 1) * 64;
    const int wc = ((wid >> 1) & 1) * 64;
    f32x4 acc0[4][4] = {}, acc1[4][4] = {};
    {
        const int srow = tid >> 2;
        const int sk = (tid & 3) * 32;
        const int grow = min(row0 + srow, M - 1);
        const unsigned short* ap = A + (size_t)grow * DHID + sk;
#pragma unroll
        for (int i = 0; i < 4; ++i) {
            short8 s = *(const short8*)(ap + i * 8);
            int g = (sk >> 3) + i;
            *(short8*)(&As[srow * 128 + ((g ^ (srow & 7)) << 3)]) = s;
        }
    }
    __syncthreads();
    const int b0base = sel ? 128 : 0;    // k : q
    const int b1base = sel ? 256 : 384;  // v : skip
#pragma unroll
    for (int ks = 0; ks < 4; ++ks) {
        short8 a[4], b0[4], b1[4];
#pragma unroll
        for (int m = 0; m < 4; ++m) {
            int r = wr + m * 16 + (lane & 15);
            int g = ks * 4 + (lane >> 4);
            a[m] = *(const short8*)(&As[r * 128 + ((g ^ (r & 7)) << 3)]);
        }
#pragma unroll
        for (int n = 0; n < 4; ++n) {
            int rb = wc + n * 16 + (lane & 15);
            b0[n] = *(const short8*)(Wt + (size_t)(b0base + rb) * DHID + ks * 32 + (lane >> 4) * 8);
            b1[n] = *(const short8*)(Wt + (size_t)(b1base + rb) * DHID + ks * 32 + (lane >> 4) * 8);
        }
#pragma unroll
        for (int m = 0; m < 4; ++m)
#pragma unroll
            for (int n = 0; n < 4; ++n) {
                acc0[m][n] = __builtin_amdgcn_mfma_f32_16x16x32_bf16(a[m], b0[n], acc0[m][n], 0, 0, 0);
                acc1[m][n] = __builtin_amdgcn_mfma_f32_16x16x32_bf16(a[m], b1[n], acc1[m][n], 0, 0, 0);
            }
    }
    const float* bias0 = sel ? bk : bq;
    const float* bias1 = sel ? bv : bs;
#pragma unroll
    for (int n = 0; n < 4; ++n) {
        int c = wc + n * 16 + (lane & 15);
        float bb0 = bias0[c];
        float bb1 = bias1[c];
#pragma unroll
        for (int m = 0; m < 4; ++m)
#pragma unroll
            for (int j = 0; j < 4; ++j) {
                int r = row0 + wr + m * 16 + (lane >> 4) * 4 + j;
                float v0 = acc0[m][n][j] + bb0;
                float v1 = acc1[m][n][j] + bb1;
                float n0 = __shfl_xor(v0, 1);
                float n1 = __shfl_xor(v1, 1);
                if (!(lane & 1) && r < M) {
                    if (sel == 0) {
                        q32[(size_t)r * 64 + (c >> 1)] = packbf(v0, n0);
                        xr32[(size_t)r * 64 + (c >> 1)] = packbf(v1, n1);
                    } else {
                        unsigned u = (unsigned)__builtin_amdgcn_cvt_pk_fp8_f32(v0, n0, 0, false);
                        u = (unsigned)__builtin_amdgcn_cvt_pk_fp8_f32(v1, n1, (int)u, true);
                        kv[(size_t)r * 64 + (c >> 1)] = u;
                    }
                }
            }
    }
}

// ---------------- per-node attention + beta-gate + GELU + LayerNorm (one wave per node) ----------------
// lane owns channels (2*lane, 2*lane+1); head = lane>>4. kv fp8-packed. houtb may alias res32 (same-wave RAW only).
__global__ __launch_bounds__(256) void node_attn_fuse(const unsigned* __restrict__ q32,
                                                      const unsigned* __restrict__ kv, const int2* __restrict__ esrc,
                                                      const float* __restrict__ We, const int* __restrict__ row_ptr,
                                                      const unsigned* __restrict__ xr32, const unsigned* res32,
                                                      const float* __restrict__ Wb, const float* __restrict__ lng,
                                                      const float* __restrict__ lnb, unsigned* houtb, float* houtf) {
    const int wid = (blockIdx.x * blockDim.x + threadIdx.x) >> 6;
    const int lane = threadIdx.x & 63;
    if (wid >= NNODES) return;
    const int base = row_ptr[wid], end = row_ptr[wid + 1];
    const int c0 = 2 * lane;
    const float2 wev = *(const float2*)(We + c0);
    const unsigned qw = q32[(size_t)wid * 64 + lane];
    const float q0 = bf2f((unsigned short)qw), q1 = bf2f((unsigned short)(qw >> 16));
    float m = -INFINITY, sden = 0.f, a0 = 0.f, a1 = 0.f;
    const float rsc = 0.17677669529663689f;  // 1/sqrt(32)
    for (int cb = base; cb < end; cb += 64) {
        int cnt = min(end - cb, 64);
        int s_l = 0;
        float a_l = 0.f;
        if (lane < cnt) {
            int2 sa = esrc[cb + lane];
            s_l = sa.x;
            a_l = __int_as_float(sa.y);
        }
        for (int j = 0; j < cnt; ++j) {
            int sN = __shfl(s_l, j);
            float av = __shfl(a_l, j);
            unsigned w = kv[(size_t)sN * 64 + lane];
            f32x2 kk = __builtin_amdgcn_cvt_pk_f32_fp8((int)w, false);
            f32x2 vv = __builtin_amdgcn_cvt_pk_f32_fp8((int)w, true);
            float kj0 = kk.x + av * wev.x, kj1 = kk.y + av * wev.y;
            float vj0 = vv.x + av * wev.x, vj1 = vv.y + av * wev.y;
            float p = q0 * kj0 + q1 * kj1;
            p += __shfl_xor(p, 1);
            p += __shfl_xor(p, 2);
            p += __shfl_xor(p, 4);
            p += __shfl_xor(p, 8);
            p *= rsc;
            float mn = fmaxf(m, p);
            float wgt = __expf(p - mn);
            float sc = __expf(m - mn);
            sden = sden * sc + wgt;
            a0 = a0 * sc + wgt * vj0;
            a1 = a1 * sc + wgt * vj1;
            m = mn;
        }
    }
    float o0 = a0 / (sden + 1e-16f), o1 = a1 / (sden + 1e-16f);
    const unsigned xw = xr32[(size_t)wid * 64 + lane];
    const float x0 = bf2f((unsigned short)xw), x1 = bf2f((unsigned short)(xw >> 16));
    const float2 w0 = *(const float2*)(Wb + c0);
    const float2 w1 = *(const float2*)(Wb + 128 + c0);
    const float2 w2 = *(const float2*)(Wb + 256 + c0);
    float bl = o0 * w0.x + o1 * w0.y + x0 * w1.x + x1 * w1.y + (o0 - x0) * w2.x + (o1 - x1) * w2.y;
#pragma unroll
    for (int off = 32; off; off >>= 1) bl += __shfl_xor(bl, off);
    float beta = 1.f / (1.f + __expf(-bl));
    float g0 = beta * x0 + (1.f - beta) * o0;
    float g1 = beta * x1 + (1.f - beta) * o1;
    g0 = 0.5f * g0 * (1.f + erff(g0 * 0.70710678118654752f));
    g1 = 0.5f * g1 * (1.f + erff(g1 * 0.70710678118654752f));
    const unsigned rw = res32[(size_t)wid * 64 + lane];
    float t0 = g0 + bf2f((unsigned short)rw);
    float t1 = g1 + bf2f((unsigned short)(rw >> 16));
    float su = t0 + t1, sq = t0 * t0 + t1 * t1;
#pragma unroll
    for (int off = 32; off; off >>= 1) {
        su += __shfl_xor(su, off);
        sq += __shfl_xor(sq, off);
    }
    float mu = su * (1.f / 128.f);
    float var = sq * (1.f / 128.f) - mu * mu;
    float inv = rsqrtf(var + 1e-5f);
    const float2 gv = *(const float2*)(lng + c0);
    const float2 bv2 = *(const float2*)(lnb + c0);
    float ov0 = (t0 - mu) * inv * gv.x + bv2.x;
    float ov1 = (t1 - mu) * inv * gv.y + bv2.y;
    if (houtf) {
        *(float2*)(houtf + (size_t)wid * 128 + c0) = make_float2(ov0, ov1);
    } else {
        houtb[(size_t)wid * 64 + lane] = packbf(ov0, ov1);
    }
}

extern "C" void kernel_launch(void* const* d_in, const int* in_sizes, int n_in, void* d_out, int out_size,
                              void* d_ws, size_t ws_size, hipStream_t stream) {
    const float* x = (const float*)d_in[0];
    const int* ei = (const int*)d_in[1];
    const float* ea = (const float*)d_in[2];
    const float* Wi = (const float*)d_in[3];
    const float* bi = (const float*)d_in[4];
    const float* Wq = (const float*)d_in[5];
    const float* bq = (const float*)d_in[6];
    const float* Wk = (const float*)d_in[7];
    const float* bk = (const float*)d_in[8];
    const float* Wv = (const float*)d_in[9];
    const float* bv = (const float*)d_in[10];
    const float* We = (const float*)d_in[11];
    const float* Wskip = (const float*)d_in[12];
    const float* bskip = (const float*)d_in[13];
    const float* Wbeta = (const float*)d_in[14];
    const float* lng = (const float*)d_in[15];
    const float* lnb = (const float*)d_in[16];

    const int* srcp = ei;
    const int* dstp = ei + NEDGES;

    char* p = (char*)d_ws;
    auto alloc = [&](size_t bytes) {
        void* r = (void*)p;
        p += (bytes + 255) & ~(size_t)255;
        return r;
    };
    unsigned* h32 = (unsigned*)alloc((size_t)NNODES * 64 * 4);
    unsigned* q32 = (unsigned*)alloc((size_t)NNODES * 64 * 4);
    unsigned* xr32 = (unsigned*)alloc((size_t)NNODES * 64 * 4);
    unsigned* kv = (unsigned*)alloc((size_t)NNODES * 64 * 4);
    unsigned short* Wit = (unsigned short*)alloc((size_t)DHID * DIN * 2);
    unsigned short* Wt3 = (unsigned short*)alloc((size_t)3 * 512 * DHID * 2);
    int* counts = (int*)alloc((size_t)NNODES * 4);
    int* row_ptr = (int*)alloc((size_t)(NNODES + 1) * 4);
    int2* esrc = (int2*)alloc((size_t)NEDGES * 8);
    int* partials = (int*)alloc(256 * 4);

    const int EB = (NEDGES + 255) / 256;
    const int NB = (NNODES + 255) / 256;
    const int GB = (NNODES + 127) / 128;       // 391
    const int WB = (NNODES * 64 + 255) / 256;  // 12500

    // weight prep
    prep_wi<<<(DHID * DIN + 255) / 256, 256, 0, stream>>>(Wi, Wit);
    prep_wqkvs<<<(3 * 512 * DHID + 255) / 256, 256, 0, stream>>>(Wq, Wk, Wv, Wskip, Wt3);

    // CSR by dst
    hipMemsetAsync(counts, 0, (size_t)NNODES * 4, stream);
    k_hist<<<EB, 256, 0, stream>>>(dstp, counts);
    k_scan_block<<<NB, 256, 0, stream>>>(counts, row_ptr + 1, partials, NNODES);
    k_scan_partials<<<1, 256, 0, stream>>>(partials, NB);
    k_apply<<<NB, 256, 0, stream>>>(partials, row_ptr, NNODES);
    hipMemsetAsync(counts, 0, (size_t)NNODES * 4, stream);
    k_scatter<<<EB, 256, 0, stream>>>(srcp, dstp, ea, row_ptr, counts, esrc);

    gemm_in<<<GB, 256, 0, stream>>>(x, Wit, bi, h32, NNODES);

    for (int l = 0; l < 3; ++l) {
        const size_t bo = (size_t)l * 128;
        gemm_qkvs<<<GB, 512, 0, stream>>>((const unsigned short*)h32, Wt3 + (size_t)l * 512 * DHID, bq + bo, bk + bo,
                                          bv + bo, bskip + bo, q32, kv, xr32, NNODES);
        node_attn_fuse<<<WB, 256, 0, stream>>>(q32, kv, esrc, We + bo, row_ptr, xr32, h32,
                                               Wbeta + (size_t)l * 384, lng + bo, lnb + bo, h32,
                                               (l == 2) ? (float*)d_out : nullptr);
    }
}

// Round 7
// 400.867 us; speedup vs baseline: 2.5232x; 1.2165x over previous
//
#include <hip/hip_runtime.h>
#include <math.h>

#define NNODES 50000
#define NEDGES 800000
#define DIN 256
#define DHID 128

typedef __attribute__((ext_vector_type(8))) short short8;
typedef __attribute__((ext_vector_type(4))) float f32x4;
typedef __attribute__((ext_vector_type(2))) float f32x2;

__device__ __forceinline__ unsigned short f2bf(float f) {
    unsigned u = __builtin_bit_cast(unsigned, f);
    u += 0x7fffu + ((u >> 16) & 1u);  // RNE
    return (unsigned short)(u >> 16);
}
__device__ __forceinline__ float bf2f(unsigned short s) {
    return __builtin_bit_cast(float, (unsigned)s << 16);
}
__device__ __forceinline__ unsigned packbf(float a, float b) {
    return (unsigned)f2bf(a) | ((unsigned)f2bf(b) << 16);
}

// ---------------- CSR build ----------------
__global__ __launch_bounds__(256) void k_hist(const int* __restrict__ dst, int* __restrict__ counts) {
    int e = blockIdx.x * 256 + threadIdx.x;
    if (e < NEDGES) atomicAdd(&counts[dst[e]], 1);
}

__global__ __launch_bounds__(256) void k_scan_block(const int* __restrict__ in, int* __restrict__ out,
                                                    int* __restrict__ partials, int n) {
    __shared__ int sh[256];
    int tid = threadIdx.x;
    int i = blockIdx.x * 256 + tid;
    int vv = (i < n) ? in[i] : 0;
    sh[tid] = vv;
    __syncthreads();
    for (int off = 1; off < 256; off <<= 1) {
        int t = (tid >= off) ? sh[tid - off] : 0;
        __syncthreads();
        sh[tid] += t;
        __syncthreads();
    }
    if (i < n) out[i] = sh[tid];
    if (tid == 255) partials[blockIdx.x] = sh[255];
}

__global__ __launch_bounds__(256) void k_scan_partials(int* __restrict__ partials, int nb) {
    __shared__ int sh[256];
    int tid = threadIdx.x;
    int vv = (tid < nb) ? partials[tid] : 0;
    sh[tid] = vv;
    __syncthreads();
    for (int off = 1; off < 256; off <<= 1) {
        int t = (tid >= off) ? sh[tid - off] : 0;
        __syncthreads();
        sh[tid] += t;
        __syncthreads();
    }
    if (tid < nb) partials[tid] = sh[tid];
}

__global__ __launch_bounds__(256) void k_apply(const int* __restrict__ partials, int* __restrict__ row_ptr, int n) {
    int i = blockIdx.x * 256 + threadIdx.x;
    if (i < n) {
        int add = blockIdx.x ? partials[blockIdx.x - 1] : 0;
        row_ptr[i + 1] += add;
    }
    if (i == 0) row_ptr[0] = 0;
}

// dst-sorted (src, ea) pairs
__global__ __launch_bounds__(256) void k_scatter(const int* __restrict__ src, const int* __restrict__ dst,
                                                 const float* __restrict__ ea, const int* __restrict__ row_ptr,
                                                 int* __restrict__ fill, int2* __restrict__ esrc) {
    int e = blockIdx.x * 256 + threadIdx.x;
    if (e < NEDGES) {
        int d = dst[e];
        int pos = row_ptr[d] + atomicAdd(&fill[d], 1);
        esrc[pos] = make_int2(src[e], __float_as_int(ea[e]));
    }
}

// ---------------- weight prep: transpose + bf16 cast ----------------
__global__ __launch_bounds__(256) void prep_wi(const float* __restrict__ Wi, unsigned short* __restrict__ Wit) {
    int idx = blockIdx.x * 256 + threadIdx.x;  // n*256 + k
    if (idx >= DHID * DIN) return;
    int n = idx >> 8, kk = idx & 255;
    Wit[idx] = f2bf(Wi[kk * DHID + n]);
}

// Wt3[l][512][128]: rows 0-127 Wq^T, 128-255 Wk^T, 256-383 Wv^T, 384-511 Wskip^T
__global__ __launch_bounds__(256) void prep_wqkvs(const float* __restrict__ Wq, const float* __restrict__ Wk,
                                                  const float* __restrict__ Wv, const float* __restrict__ Ws,
                                                  unsigned short* __restrict__ out) {
    int idx = blockIdx.x * 256 + threadIdx.x;
    if (idx >= 3 * 512 * DHID) return;
    int l = idx / (512 * DHID);
    int rem = idx - l * 512 * DHID;
    int r = rem >> 7;  // 0..511
    int kk = rem & 127;
    int sel = r >> 7, rl = r & 127;
    const float* srcm = sel == 0 ? Wq : sel == 1 ? Wk : sel == 2 ? Wv : Ws;
    out[idx] = f2bf(srcm[l * DHID * DHID + kk * DHID + rl]);
}

// ---------------- input projection: h[M,128](bf16) = x[M,256] @ Wi + bi ----------------
__global__ __launch_bounds__(256) void gemm_in(const float* __restrict__ A, const unsigned short* __restrict__ Wt,
                                               const float* __restrict__ bias, unsigned* __restrict__ h32, int M) {
    __shared__ short As[128 * 128];
    const int tid = threadIdx.x;
    const int lane = tid & 63;
    const int wid = tid >> 6;
    const int row0 = blockIdx.x * 128;
    const int wr = (wid & 1) * 64;
    const int wc = (wid >> 1) * 64;
    f32x4 acc[4][4] = {};
    const int srow = tid >> 1;
    const int sk = (tid & 1) * 64;
    const int grow = min(row0 + srow, M - 1);
    for (int kt = 0; kt < 2; ++kt) {
        const float* ap = A + (size_t)grow * DIN + kt * 128 + sk;
#pragma unroll
        for (int i = 0; i < 8; ++i) {
            float4 f0 = *(const float4*)(ap + i * 8);
            float4 f1 = *(const float4*)(ap + i * 8 + 4);
            short8 s;
            s[0] = f2bf(f0.x); s[1] = f2bf(f0.y); s[2] = f2bf(f0.z); s[3] = f2bf(f0.w);
            s[4] = f2bf(f1.x); s[5] = f2bf(f1.y); s[6] = f2bf(f1.z); s[7] = f2bf(f1.w);
            int g = (sk >> 3) + i;
            *(short8*)(&As[srow * 128 + ((g ^ (srow & 7)) << 3)]) = s;
        }
        __syncthreads();
#pragma unroll
        for (int ks = 0; ks < 4; ++ks) {
            short8 a[4], b[4];
#pragma unroll
            for (int m = 0; m < 4; ++m) {
                int r = wr + m * 16 + (lane & 15);
                int g = ks * 4 + (lane >> 4);
                a[m] = *(const short8*)(&As[r * 128 + ((g ^ (r & 7)) << 3)]);
            }
#pragma unroll
            for (int n = 0; n < 4; ++n) {
                int c = wc + n * 16 + (lane & 15);
                b[n] = *(const short8*)(Wt + (size_t)c * DIN + kt * 128 + ks * 32 + (lane >> 4) * 8);
            }
#pragma unroll
            for (int m = 0; m < 4; ++m)
#pragma unroll
                for (int n = 0; n < 4; ++n)
                    acc[m][n] = __builtin_amdgcn_mfma_f32_16x16x32_bf16(a[m], b[n], acc[m][n], 0, 0, 0);
        }
        __syncthreads();
    }
#pragma unroll
    for (int n = 0; n < 4; ++n) {
        int c = wc + n * 16 + (lane & 15);
        float bb = bias[c];
#pragma unroll
        for (int m = 0; m < 4; ++m)
#pragma unroll
            for (int j = 0; j < 4; ++j) {
                int r = row0 + wr + m * 16 + (lane >> 4) * 4 + j;
                float val = acc[m][n][j] + bb;
                float nb = __shfl_xor(val, 1);
                if (!(lane & 1) && r < M) h32[(size_t)r * 64 + (c >> 1)] = packbf(val, nb);
            }
    }
}

// ---------------- fused q/k/v/skip GEMM from bf16 h ----------------
// 8 waves: (wr, wc) 2x2 tile grid x sel: sel=0 computes q+skip, sel=1 computes k+v (packed fp8 kv)
__global__ __launch_bounds__(512) void gemm_qkvs(const unsigned short* __restrict__ A,
                                                 const unsigned short* __restrict__ Wt, const float* __restrict__ bq,
                                                 const float* __restrict__ bk, const float* __restrict__ bv,
                                                 const float* __restrict__ bs, unsigned* __restrict__ q32,
                                                 unsigned* __restrict__ kv, unsigned* __restrict__ xr32, int M) {
    __shared__ short As[128 * 128];
    const int tid = threadIdx.x;
    const int lane = tid & 63;
    const int wid = tid >> 6;
    const int row0 = blockIdx.x * 128;
    const int sel = wid >> 2;  // 0: q/skip, 1: k/v
    const int wr = (wid & 1) * 64;
    const int wc = ((wid >> 1) & 1) * 64;
    f32x4 acc0[4][4] = {}, acc1[4][4] = {};
    {
        const int srow = tid >> 2;
        const int sk = (tid & 3) * 32;
        const int grow = min(row0 + srow, M - 1);
        const unsigned short* ap = A + (size_t)grow * DHID + sk;
#pragma unroll
        for (int i = 0; i < 4; ++i) {
            short8 s = *(const short8*)(ap + i * 8);
            int g = (sk >> 3) + i;
            *(short8*)(&As[srow * 128 + ((g ^ (srow & 7)) << 3)]) = s;
        }
    }
    __syncthreads();
    const int b0base = sel ? 128 : 0;    // k : q
    const int b1base = sel ? 256 : 384;  // v : skip
#pragma unroll
    for (int ks = 0; ks < 4; ++ks) {
        short8 a[4], b0[4], b1[4];
#pragma unroll
        for (int m = 0; m < 4; ++m) {
            int r = wr + m * 16 + (lane & 15);
            int g = ks * 4 + (lane >> 4);
            a[m] = *(const short8*)(&As[r * 128 + ((g ^ (r & 7)) << 3)]);
        }
#pragma unroll
        for (int n = 0; n < 4; ++n) {
            int rb = wc + n * 16 + (lane & 15);
            b0[n] = *(const short8*)(Wt + (size_t)(b0base + rb) * DHID + ks * 32 + (lane >> 4) * 8);
            b1[n] = *(const short8*)(Wt + (size_t)(b1base + rb) * DHID + ks * 32 + (lane >> 4) * 8);
        }
#pragma unroll
        for (int m = 0; m < 4; ++m)
#pragma unroll
            for (int n = 0; n < 4; ++n) {
                acc0[m][n] = __builtin_amdgcn_mfma_f32_16x16x32_bf16(a[m], b0[n], acc0[m][n], 0, 0, 0);
                acc1[m][n] = __builtin_amdgcn_mfma_f32_16x16x32_bf16(a[m], b1[n], acc1[m][n], 0, 0, 0);
            }
    }
    const float* bias0 = sel ? bk : bq;
    const float* bias1 = sel ? bv : bs;
#pragma unroll
    for (int n = 0; n < 4; ++n) {
        int c = wc + n * 16 + (lane & 15);
        float bb0 = bias0[c];
        float bb1 = bias1[c];
#pragma unroll
        for (int m = 0; m < 4; ++m)
#pragma unroll
            for (int j = 0; j < 4; ++j) {
                int r = row0 + wr + m * 16 + (lane >> 4) * 4 + j;
                float v0 = acc0[m][n][j] + bb0;
                float v1 = acc1[m][n][j] + bb1;
                float n0 = __shfl_xor(v0, 1);
                float n1 = __shfl_xor(v1, 1);
                if (!(lane & 1) && r < M) {
                    if (sel == 0) {
                        q32[(size_t)r * 64 + (c >> 1)] = packbf(v0, n0);
                        xr32[(size_t)r * 64 + (c >> 1)] = packbf(v1, n1);
                    } else {
                        unsigned u = (unsigned)__builtin_amdgcn_cvt_pk_fp8_f32(v0, n0, 0, false);
                        u = (unsigned)__builtin_amdgcn_cvt_pk_fp8_f32(v1, n1, (int)u, true);
                        kv[(size_t)r * 64 + (c >> 1)] = u;
                    }
                }
            }
    }
}

// ---------------- per-node attention + beta-gate + GELU + LayerNorm ----------------
// One wave per node. Inner loop: 4 edge-subgroups (g=lane>>4), lane owns 8 channels (4 kv dwords).
// Online softmax in exp2 domain (log2e*rsc folded into q). Epilogue re-split to 2 ch/lane via LDS.
// houtb may alias res32 (same-wave RAW only).
__global__ __launch_bounds__(256) void node_attn_fuse(const unsigned* __restrict__ q32,
                                                      const unsigned* __restrict__ kv, const int2* __restrict__ esrc,
                                                      const float* __restrict__ We, const int* __restrict__ row_ptr,
                                                      const unsigned* __restrict__ xr32, const unsigned* res32,
                                                      const float* __restrict__ Wb, const float* __restrict__ lng,
                                                      const float* __restrict__ lnb, unsigned* houtb, float* houtf) {
    __shared__ float sh_o[4][128];
    const int tid = threadIdx.x;
    const int wv = tid >> 6;
    const int lane = tid & 63;
    const int wid = blockIdx.x * 4 + wv;
    if (wid >= NNODES) return;
    const int ln = lane & 15;  // channel group: channels 8*ln .. 8*ln+7
    const int g = lane >> 4;   // edge subgroup 0..3
    const int base = row_ptr[wid], end = row_ptr[wid + 1];
    const float SC = 0.25505654047688565f;  // (1/sqrt(32)) * log2(e)

    float qv[8], wev[8];
    {
        uint4 qw = *(const uint4*)(q32 + (size_t)wid * 64 + 4 * ln);
#pragma unroll
        for (int t = 0; t < 4; ++t) {
            unsigned u = ((const unsigned*)&qw)[t];
            qv[2 * t] = bf2f((unsigned short)u) * SC;
            qv[2 * t + 1] = bf2f((unsigned short)(u >> 16)) * SC;
        }
        float4 wlo = *(const float4*)(We + 8 * ln);
        float4 whi = *(const float4*)(We + 8 * ln + 4);
        wev[0] = wlo.x; wev[1] = wlo.y; wev[2] = wlo.z; wev[3] = wlo.w;
        wev[4] = whi.x; wev[5] = whi.y; wev[6] = whi.z; wev[7] = whi.w;
    }

    float m = -1e30f, sden = 0.f;
    float acc[8] = {};

    for (int cb = base; cb < end; cb += 64) {
        int cnt = min(end - cb, 64);
        int s_l = 0;
        float a_l = 0.f;
        if (lane < cnt) {
            int2 sa = esrc[cb + lane];
            s_l = sa.x;
            a_l = __int_as_float(sa.y);
        }
        int jmax = (cnt + 3) >> 2;
        for (int j = 0; j < jmax; ++j) {
            int slot = j * 4 + g;  // <= 63 always
            bool valid = slot < cnt;
            int sN = __shfl(s_l, slot);
            float av = __shfl(a_l, slot);
            if (!valid) sN = 0;
            uint4 kvw = *(const uint4*)(kv + (size_t)sN * 64 + 4 * ln);
            float vj[8];
            float p = 0.f;
#pragma unroll
            for (int t = 0; t < 4; ++t) {
                unsigned u = ((const unsigned*)&kvw)[t];
                f32x2 kk = __builtin_amdgcn_cvt_pk_f32_fp8((int)u, false);
                f32x2 vv = __builtin_amdgcn_cvt_pk_f32_fp8((int)u, true);
                float kj0 = fmaf(av, wev[2 * t], kk.x);
                float kj1 = fmaf(av, wev[2 * t + 1], kk.y);
                vj[2 * t] = fmaf(av, wev[2 * t], vv.x);
                vj[2 * t + 1] = fmaf(av, wev[2 * t + 1], vv.y);
                p = fmaf(qv[2 * t], kj0, p);
                p = fmaf(qv[2 * t + 1], kj1, p);
            }
            // head dot: sum over 4 lanes (32 channels); lanes xor 1,2 stay within head & subgroup
            p += __shfl_xor(p, 1);
            p += __shfl_xor(p, 2);
            p = valid ? p : -3e38f;
            float mn = fmaxf(m, p);
            float wgt = exp2f(p - mn);
            if (__any(mn > m)) {
                float sc = exp2f(m - mn);
                sden = fmaf(sden, sc, wgt);
#pragma unroll
                for (int i = 0; i < 8; ++i) acc[i] = fmaf(acc[i], sc, wgt * vj[i]);
                m = mn;
            } else {
                sden += wgt;
#pragma unroll
                for (int i = 0; i < 8; ++i) acc[i] = fmaf(wgt, vj[i], acc[i]);
            }
        }
    }

    // merge the 4 subgroup partial states (lanes ln, ln+16, ln+32, ln+48 share channels & head)
#pragma unroll
    for (int off = 16; off <= 32; off <<= 1) {
        float m_o = __shfl_xor(m, off);
        float sden_o = __shfl_xor(sden, off);
        float mn = fmaxf(m, m_o);
        float sa = exp2f(m - mn), sb = exp2f(m_o - mn);
        sden = sden * sa + sden_o * sb;
#pragma unroll
        for (int i = 0; i < 8; ++i) acc[i] = acc[i] * sa + __shfl_xor(acc[i], off) * sb;
        m = mn;
    }
    float rden = 1.f / (sden + 1e-16f);
    if (g == 0) {
#pragma unroll
        for (int i = 0; i < 8; ++i) sh_o[wv][8 * ln + i] = acc[i] * rden;
    }
    __asm__ volatile("s_waitcnt lgkmcnt(0)" ::: "memory");  // same-wave LDS RAW

    // ---- epilogue: lane owns channels (2*lane, 2*lane+1) ----
    const int c0 = 2 * lane;
    const float2 ov0v = *(const float2*)(&sh_o[wv][c0]);
    float o0 = ov0v.x, o1 = ov0v.y;
    const unsigned xw = xr32[(size_t)wid * 64 + lane];
    const float x0 = bf2f((unsigned short)xw), x1 = bf2f((unsigned short)(xw >> 16));
    const float2 w0 = *(const float2*)(Wb + c0);
    const float2 w1 = *(const float2*)(Wb + 128 + c0);
    const float2 w2 = *(const float2*)(Wb + 256 + c0);
    float bl = o0 * w0.x + o1 * w0.y + x0 * w1.x + x1 * w1.y + (o0 - x0) * w2.x + (o1 - x1) * w2.y;
#pragma unroll
    for (int off = 32; off; off >>= 1) bl += __shfl_xor(bl, off);
    float beta = 1.f / (1.f + __expf(-bl));
    float g0 = beta * x0 + (1.f - beta) * o0;
    float g1 = beta * x1 + (1.f - beta) * o1;
    g0 = 0.5f * g0 * (1.f + erff(g0 * 0.70710678118654752f));
    g1 = 0.5f * g1 * (1.f + erff(g1 * 0.70710678118654752f));
    const unsigned rw = res32[(size_t)wid * 64 + lane];
    float t0 = g0 + bf2f((unsigned short)rw);
    float t1 = g1 + bf2f((unsigned short)(rw >> 16));
    float su = t0 + t1, sq = t0 * t0 + t1 * t1;
#pragma unroll
    for (int off = 32; off; off >>= 1) {
        su += __shfl_xor(su, off);
        sq += __shfl_xor(sq, off);
    }
    float mu = su * (1.f / 128.f);
    float var = sq * (1.f / 128.f) - mu * mu;
    float inv = rsqrtf(var + 1e-5f);
    const float2 gv = *(const float2*)(lng + c0);
    const float2 bv2 = *(const float2*)(lnb + c0);
    float ovx = (t0 - mu) * inv * gv.x + bv2.x;
    float ovy = (t1 - mu) * inv * gv.y + bv2.y;
    if (houtf) {
        *(float2*)(houtf + (size_t)wid * 128 + c0) = make_float2(ovx, ovy);
    } else {
        houtb[(size_t)wid * 64 + lane] = packbf(ovx, ovy);
    }
}

extern "C" void kernel_launch(void* const* d_in, const int* in_sizes, int n_in, void* d_out, int out_size,
                              void* d_ws, size_t ws_size, hipStream_t stream) {
    const float* x = (const float*)d_in[0];
    const int* ei = (const int*)d_in[1];
    const float* ea = (const float*)d_in[2];
    const float* Wi = (const float*)d_in[3];
    const float* bi = (const float*)d_in[4];
    const float* Wq = (const float*)d_in[5];
    const float* bq = (const float*)d_in[6];
    const float* Wk = (const float*)d_in[7];
    const float* bk = (const float*)d_in[8];
    const float* Wv = (const float*)d_in[9];
    const float* bv = (const float*)d_in[10];
    const float* We = (const float*)d_in[11];
    const float* Wskip = (const float*)d_in[12];
    const float* bskip = (const float*)d_in[13];
    const float* Wbeta = (const float*)d_in[14];
    const float* lng = (const float*)d_in[15];
    const float* lnb = (const float*)d_in[16];

    const int* srcp = ei;
    const int* dstp = ei + NEDGES;

    char* p = (char*)d_ws;
    auto alloc = [&](size_t bytes) {
        void* r = (void*)p;
        p += (bytes + 255) & ~(size_t)255;
        return r;
    };
    unsigned* h32 = (unsigned*)alloc((size_t)NNODES * 64 * 4);
    unsigned* q32 = (unsigned*)alloc((size_t)NNODES * 64 * 4);
    unsigned* xr32 = (unsigned*)alloc((size_t)NNODES * 64 * 4);
    unsigned* kv = (unsigned*)alloc((size_t)NNODES * 64 * 4);
    unsigned short* Wit = (unsigned short*)alloc((size_t)DHID * DIN * 2);
    unsigned short* Wt3 = (unsigned short*)alloc((size_t)3 * 512 * DHID * 2);
    int* counts = (int*)alloc((size_t)NNODES * 4);
    int* row_ptr = (int*)alloc((size_t)(NNODES + 1) * 4);
    int2* esrc = (int2*)alloc((size_t)NEDGES * 8);
    int* partials = (int*)alloc(256 * 4);

    const int EB = (NEDGES + 255) / 256;
    const int NB = (NNODES + 255) / 256;
    const int GB = (NNODES + 127) / 128;  // 391
    const int WB = (NNODES + 3) / 4;      // 12500 (4 waves/block, 1 node/wave)

    // weight prep
    prep_wi<<<(DHID * DIN + 255) / 256, 256, 0, stream>>>(Wi, Wit);
    prep_wqkvs<<<(3 * 512 * DHID + 255) / 256, 256, 0, stream>>>(Wq, Wk, Wv, Wskip, Wt3);

    // CSR by dst
    hipMemsetAsync(counts, 0, (size_t)NNODES * 4, stream);
    k_hist<<<EB, 256, 0, stream>>>(dstp, counts);
    k_scan_block<<<NB, 256, 0, stream>>>(counts, row_ptr + 1, partials, NNODES);
    k_scan_partials<<<1, 256, 0, stream>>>(partials, NB);
    k_apply<<<NB, 256, 0, stream>>>(partials, row_ptr, NNODES);
    hipMemsetAsync(counts, 0, (size_t)NNODES * 4, stream);
    k_scatter<<<EB, 256, 0, stream>>>(srcp, dstp, ea, row_ptr, counts, esrc);

    gemm_in<<<GB, 256, 0, stream>>>(x, Wit, bi, h32, NNODES);

    for (int l = 0; l < 3; ++l) {
        const size_t bo = (size_t)l * 128;
        gemm_qkvs<<<GB, 512, 0, stream>>>((const unsigned short*)h32, Wt3 + (size_t)l * 512 * DHID, bq + bo, bk + bo,
                                          bv + bo, bskip + bo, q32, kv, xr32, NNODES);
        node_attn_fuse<<<WB, 256, 0, stream>>>(q32, kv, esrc, We + bo, row_ptr, xr32, h32,
                                               Wbeta + (size_t)l * 384, lng + bo, lnb + bo, h32,
                                               (l == 2) ? (float*)d_out : nullptr);
    }
}

// Round 8
// 376.192 us; speedup vs baseline: 2.6887x; 1.0656x over previous
//
#include <hip/hip_runtime.h>
#include <math.h>

#define NNODES 50000
#define NEDGES 800000
#define DIN 256
#define DHID 128

typedef __attribute__((ext_vector_type(8))) short short8;
typedef __attribute__((ext_vector_type(4))) float f32x4;
typedef __attribute__((ext_vector_type(2))) float f32x2;

__device__ __forceinline__ unsigned short f2bf(float f) {
    unsigned u = __builtin_bit_cast(unsigned, f);
    u += 0x7fffu + ((u >> 16) & 1u);  // RNE
    return (unsigned short)(u >> 16);
}
__device__ __forceinline__ float bf2f(unsigned short s) {
    return __builtin_bit_cast(float, (unsigned)s << 16);
}
__device__ __forceinline__ unsigned packbf(float a, float b) {
    return (unsigned)f2bf(a) | ((unsigned)f2bf(b) << 16);
}

// ---------------- CSR build ----------------
__global__ __launch_bounds__(256) void k_hist(const int* __restrict__ dst, int* __restrict__ counts) {
    int e = blockIdx.x * 256 + threadIdx.x;
    if (e < NEDGES) atomicAdd(&counts[dst[e]], 1);
}

__global__ __launch_bounds__(256) void k_scan_block(const int* __restrict__ in, int* __restrict__ out,
                                                    int* __restrict__ partials, int n) {
    __shared__ int sh[256];
    int tid = threadIdx.x;
    int i = blockIdx.x * 256 + tid;
    int vv = (i < n) ? in[i] : 0;
    sh[tid] = vv;
    __syncthreads();
    for (int off = 1; off < 256; off <<= 1) {
        int t = (tid >= off) ? sh[tid - off] : 0;
        __syncthreads();
        sh[tid] += t;
        __syncthreads();
    }
    if (i < n) out[i] = sh[tid];
    if (tid == 255) partials[blockIdx.x] = sh[255];
}

__global__ __launch_bounds__(256) void k_scan_partials(int* __restrict__ partials, int nb) {
    __shared__ int sh[256];
    int tid = threadIdx.x;
    int vv = (tid < nb) ? partials[tid] : 0;
    sh[tid] = vv;
    __syncthreads();
    for (int off = 1; off < 256; off <<= 1) {
        int t = (tid >= off) ? sh[tid - off] : 0;
        __syncthreads();
        sh[tid] += t;
        __syncthreads();
    }
    if (tid < nb) partials[tid] = sh[tid];
}

__global__ __launch_bounds__(256) void k_apply(const int* __restrict__ partials, int* __restrict__ row_ptr, int n) {
    int i = blockIdx.x * 256 + threadIdx.x;
    if (i < n) {
        int add = blockIdx.x ? partials[blockIdx.x - 1] : 0;
        row_ptr[i + 1] += add;
    }
    if (i == 0) row_ptr[0] = 0;
}

// dst-sorted (src, ea) pairs; fill holds degrees (from hist) and is consumed by atomicSub -> no re-zero pass
__global__ __launch_bounds__(256) void k_scatter(const int* __restrict__ src, const int* __restrict__ dst,
                                                 const float* __restrict__ ea, const int* __restrict__ row_ptr,
                                                 int* __restrict__ fill, int2* __restrict__ esrc) {
    int e = blockIdx.x * 256 + threadIdx.x;
    if (e < NEDGES) {
        int d = dst[e];
        int old = atomicSub(&fill[d], 1);
        int pos = row_ptr[d] + old - 1;
        esrc[pos] = make_int2(src[e], __float_as_int(ea[e]));
    }
}

// ---------------- weight prep: transpose + bf16 cast (merged) ----------------
// Wit[n*256+k] = Wi[k][n];  Wt3[l][512][128]: rows 0-127 Wq^T, 128-255 Wk^T, 256-383 Wv^T, 384-511 Wskip^T
__global__ __launch_bounds__(256) void prep_w(const float* __restrict__ Wi, const float* __restrict__ Wq,
                                              const float* __restrict__ Wk, const float* __restrict__ Wv,
                                              const float* __restrict__ Ws, unsigned short* __restrict__ Wit,
                                              unsigned short* __restrict__ Wt3) {
    int idx = blockIdx.x * 256 + threadIdx.x;
    if (idx < DHID * DIN) {
        int n = idx >> 8, kk = idx & 255;
        Wit[idx] = f2bf(Wi[kk * DHID + n]);
    }
    int idx2 = idx - DHID * DIN;
    if (idx2 >= 0 && idx2 < 3 * 512 * DHID) {
        int l = idx2 / (512 * DHID);
        int rem = idx2 - l * 512 * DHID;
        int r = rem >> 7;
        int kk = rem & 127;
        int sel = r >> 7, rl = r & 127;
        const float* srcm = sel == 0 ? Wq : sel == 1 ? Wk : sel == 2 ? Wv : Ws;
        Wt3[idx2] = f2bf(srcm[l * DHID * DHID + kk * DHID + rl]);
    }
}

// ---------------- input projection: h[M,128](bf16) = x[M,256] @ Wi + bi ----------------
__global__ __launch_bounds__(256) void gemm_in(const float* __restrict__ A, const unsigned short* __restrict__ Wt,
                                               const float* __restrict__ bias, unsigned* __restrict__ h32, int M) {
    __shared__ short As[128 * 128];
    const int tid = threadIdx.x;
    const int lane = tid & 63;
    const int wid = tid >> 6;
    const int row0 = blockIdx.x * 128;
    const int wr = (wid & 1) * 64;
    const int wc = (wid >> 1) * 64;
    f32x4 acc[4][4] = {};
    const int srow = tid >> 1;
    const int sk = (tid & 1) * 64;
    const int grow = min(row0 + srow, M - 1);
    for (int kt = 0; kt < 2; ++kt) {
        const float* ap = A + (size_t)grow * DIN + kt * 128 + sk;
#pragma unroll
        for (int i = 0; i < 8; ++i) {
            float4 f0 = *(const float4*)(ap + i * 8);
            float4 f1 = *(const float4*)(ap + i * 8 + 4);
            short8 s;
            s[0] = f2bf(f0.x); s[1] = f2bf(f0.y); s[2] = f2bf(f0.z); s[3] = f2bf(f0.w);
            s[4] = f2bf(f1.x); s[5] = f2bf(f1.y); s[6] = f2bf(f1.z); s[7] = f2bf(f1.w);
            int g = (sk >> 3) + i;
            *(short8*)(&As[srow * 128 + ((g ^ (srow & 7)) << 3)]) = s;
        }
        __syncthreads();
#pragma unroll
        for (int ks = 0; ks < 4; ++ks) {
            short8 a[4], b[4];
#pragma unroll
            for (int m = 0; m < 4; ++m) {
                int r = wr + m * 16 + (lane & 15);
                int g = ks * 4 + (lane >> 4);
                a[m] = *(const short8*)(&As[r * 128 + ((g ^ (r & 7)) << 3)]);
            }
#pragma unroll
            for (int n = 0; n < 4; ++n) {
                int c = wc + n * 16 + (lane & 15);
                b[n] = *(const short8*)(Wt + (size_t)c * DIN + kt * 128 + ks * 32 + (lane >> 4) * 8);
            }
#pragma unroll
            for (int m = 0; m < 4; ++m)
#pragma unroll
                for (int n = 0; n < 4; ++n)
                    acc[m][n] = __builtin_amdgcn_mfma_f32_16x16x32_bf16(a[m], b[n], acc[m][n], 0, 0, 0);
        }
        __syncthreads();
    }
    // epilogue: per-wave LDS repack (reuse As) -> coalesced uint4 stores
    float* my = ((float*)As) + wid * 1024;
    float bb[4];
#pragma unroll
    for (int n = 0; n < 4; ++n) bb[n] = bias[wc + n * 16 + (lane & 15)];
    const int rr = lane >> 2;
    const int cb = lane & 3;
#pragma unroll
    for (int m = 0; m < 4; ++m) {
#pragma unroll
        for (int n = 0; n < 4; ++n) {
            int lc = n * 16 + (lane & 15);
#pragma unroll
            for (int j = 0; j < 4; ++j) {
                int row = (lane >> 4) * 4 + j;
                my[row * 64 + (((lc >> 2) ^ (row & 7)) << 2) + (lc & 3)] = acc[m][n][j] + bb[n];
            }
        }
        float vals[16];
#pragma unroll
        for (int s = 0; s < 4; ++s) {
            int gx = (cb * 4 + s) ^ (rr & 7);
            f32x4 t4 = *(const f32x4*)(my + rr * 64 + gx * 4);
            vals[s * 4 + 0] = t4.x; vals[s * 4 + 1] = t4.y; vals[s * 4 + 2] = t4.z; vals[s * 4 + 3] = t4.w;
        }
        int grow2 = row0 + wr + m * 16 + rr;
        if (grow2 < M) {
            unsigned pk[8];
#pragma unroll
            for (int d = 0; d < 8; ++d) pk[d] = packbf(vals[2 * d], vals[2 * d + 1]);
            unsigned* op = h32 + (size_t)grow2 * 64 + (wc >> 1) + cb * 8;
            *(uint4*)op = make_uint4(pk[0], pk[1], pk[2], pk[3]);
            *(uint4*)(op + 4) = make_uint4(pk[4], pk[5], pk[6], pk[7]);
        }
    }
}

// ---------------- fused q/k/v/skip GEMM from bf16 h ----------------
// 8 waves: (wr, wc) 2x2 tile grid x sel: sel=0 computes q+skip (bf16), sel=1 computes k+v (packed fp8 kv)
__global__ __launch_bounds__(512) void gemm_qkvs(const unsigned short* __restrict__ A,
                                                 const unsigned short* __restrict__ Wt, const float* __restrict__ bq,
                                                 const float* __restrict__ bk, const float* __restrict__ bv,
                                                 const float* __restrict__ bs, unsigned* __restrict__ q32,
                                                 unsigned* __restrict__ kv, unsigned* __restrict__ xr32, int M) {
    __shared__ short As[128 * 128];
    const int tid = threadIdx.x;
    const int lane = tid & 63;
    const int wid = tid >> 6;
    const int row0 = blockIdx.x * 128;
    const int sel = wid >> 2;  // 0: q/skip, 1: k/v
    const int wr = (wid & 1) * 64;
    const int wc = ((wid >> 1) & 1) * 64;
    f32x4 acc0[4][4] = {}, acc1[4][4] = {};
    {
        const int srow = tid >> 2;
        const int sk = (tid & 3) * 32;
        const int grow = min(row0 + srow, M - 1);
        const unsigned short* ap = A + (size_t)grow * DHID + sk;
#pragma unroll
        for (int i = 0; i < 4; ++i) {
            short8 s = *(const short8*)(ap + i * 8);
            int g = (sk >> 3) + i;
            *(short8*)(&As[srow * 128 + ((g ^ (srow & 7)) << 3)]) = s;
        }
    }
    __syncthreads();
    const int b0base = sel ? 128 : 0;    // k : q
    const int b1base = sel ? 256 : 384;  // v : skip
#pragma unroll
    for (int ks = 0; ks < 4; ++ks) {
        short8 a[4], b0[4], b1[4];
#pragma unroll
        for (int m = 0; m < 4; ++m) {
            int r = wr + m * 16 + (lane & 15);
            int g = ks * 4 + (lane >> 4);
            a[m] = *(const short8*)(&As[r * 128 + ((g ^ (r & 7)) << 3)]);
        }
#pragma unroll
        for (int n = 0; n < 4; ++n) {
            int rb = wc + n * 16 + (lane & 15);
            b0[n] = *(const short8*)(Wt + (size_t)(b0base + rb) * DHID + ks * 32 + (lane >> 4) * 8);
            b1[n] = *(const short8*)(Wt + (size_t)(b1base + rb) * DHID + ks * 32 + (lane >> 4) * 8);
        }
#pragma unroll
        for (int m = 0; m < 4; ++m)
#pragma unroll
            for (int n = 0; n < 4; ++n) {
                acc0[m][n] = __builtin_amdgcn_mfma_f32_16x16x32_bf16(a[m], b0[n], acc0[m][n], 0, 0, 0);
                acc1[m][n] = __builtin_amdgcn_mfma_f32_16x16x32_bf16(a[m], b1[n], acc1[m][n], 0, 0, 0);
            }
    }
    __syncthreads();  // done reading As; reuse as repack buffer
    float* my = ((float*)As) + wid * 1024;
    const float* bias0 = sel ? bk : bq;
    const float* bias1 = sel ? bv : bs;
    float bb0[4], bb1[4];
#pragma unroll
    for (int n = 0; n < 4; ++n) {
        int c = wc + n * 16 + (lane & 15);
        bb0[n] = bias0[c];
        bb1[n] = bias1[c];
    }
    const int rr = lane >> 2;
    const int cb = lane & 3;
#pragma unroll
    for (int m = 0; m < 4; ++m) {
        float vals0[16], vals1[16];
        // tensor 0 round-trip
#pragma unroll
        for (int n = 0; n < 4; ++n) {
            int lc = n * 16 + (lane & 15);
#pragma unroll
            for (int j = 0; j < 4; ++j) {
                int row = (lane >> 4) * 4 + j;
                my[row * 64 + (((lc >> 2) ^ (row & 7)) << 2) + (lc & 3)] = acc0[m][n][j] + bb0[n];
            }
        }
#pragma unroll
        for (int s = 0; s < 4; ++s) {
            int gx = (cb * 4 + s) ^ (rr & 7);
            f32x4 t4 = *(const f32x4*)(my + rr * 64 + gx * 4);
            vals0[s * 4 + 0] = t4.x; vals0[s * 4 + 1] = t4.y; vals0[s * 4 + 2] = t4.z; vals0[s * 4 + 3] = t4.w;
        }
        // tensor 1 round-trip (same region; wave LDS ops are FIFO -> no WAR hazard)
#pragma unroll
        for (int n = 0; n < 4; ++n) {
            int lc = n * 16 + (lane & 15);
#pragma unroll
            for (int j = 0; j < 4; ++j) {
                int row = (lane >> 4) * 4 + j;
                my[row * 64 + (((lc >> 2) ^ (row & 7)) << 2) + (lc & 3)] = acc1[m][n][j] + bb1[n];
            }
        }
#pragma unroll
        for (int s = 0; s < 4; ++s) {
            int gx = (cb * 4 + s) ^ (rr & 7);
            f32x4 t4 = *(const f32x4*)(my + rr * 64 + gx * 4);
            vals1[s * 4 + 0] = t4.x; vals1[s * 4 + 1] = t4.y; vals1[s * 4 + 2] = t4.z; vals1[s * 4 + 3] = t4.w;
        }
        int grow2 = row0 + wr + m * 16 + rr;
        if (grow2 < M) {
            size_t obase = (size_t)grow2 * 64 + (wc >> 1) + cb * 8;
            if (sel == 0) {
                unsigned p0[8], p1[8];
#pragma unroll
                for (int d = 0; d < 8; ++d) {
                    p0[d] = packbf(vals0[2 * d], vals0[2 * d + 1]);
                    p1[d] = packbf(vals1[2 * d], vals1[2 * d + 1]);
                }
                *(uint4*)(q32 + obase) = make_uint4(p0[0], p0[1], p0[2], p0[3]);
                *(uint4*)(q32 + obase + 4) = make_uint4(p0[4], p0[5], p0[6], p0[7]);
                *(uint4*)(xr32 + obase) = make_uint4(p1[0], p1[1], p1[2], p1[3]);
                *(uint4*)(xr32 + obase + 4) = make_uint4(p1[4], p1[5], p1[6], p1[7]);
            } else {
                unsigned pk[8];
#pragma unroll
                for (int d = 0; d < 8; ++d) {
                    unsigned u = (unsigned)__builtin_amdgcn_cvt_pk_fp8_f32(vals0[2 * d], vals0[2 * d + 1], 0, false);
                    u = (unsigned)__builtin_amdgcn_cvt_pk_fp8_f32(vals1[2 * d], vals1[2 * d + 1], (int)u, true);
                    pk[d] = u;
                }
                *(uint4*)(kv + obase) = make_uint4(pk[0], pk[1], pk[2], pk[3]);
                *(uint4*)(kv + obase + 4) = make_uint4(pk[4], pk[5], pk[6], pk[7]);
            }
        }
    }
}

// ---------------- per-node attention + beta-gate + GELU + LayerNorm ----------------
// One wave per node; 4 edge-subgroups (g=lane>>4), lane owns 8 channels (4 kv dwords).
// Algebra: logit = q·k + av*(q·we);  out = (Σw·v + (Σw·av)·we)/Σw  -> no per-edge kj/vj construction.
// exp2-domain online softmax with defer-max threshold. houtb may alias res32 (same-wave RAW only).
__global__ __launch_bounds__(256) void node_attn_fuse(const unsigned* __restrict__ q32,
                                                      const unsigned* __restrict__ kv, const int2* __restrict__ esrc,
                                                      const float* __restrict__ We, const int* __restrict__ row_ptr,
                                                      const unsigned* __restrict__ xr32, const unsigned* res32,
                                                      const float* __restrict__ Wb, const float* __restrict__ lng,
                                                      const float* __restrict__ lnb, unsigned* houtb, float* houtf) {
    __shared__ float sh_o[4][128];
    const int tid = threadIdx.x;
    const int wv = tid >> 6;
    const int lane = tid & 63;
    const int wid = blockIdx.x * 4 + wv;
    if (wid >= NNODES) return;
    const int ln = lane & 15;  // channel group: channels 8*ln .. 8*ln+7
    const int g = lane >> 4;   // edge subgroup 0..3
    const int base = row_ptr[wid], end = row_ptr[wid + 1];
    const float SC = 0.25505654047688565f;  // (1/sqrt(32)) * log2(e)
    const float THR = 8.0f;                 // defer-max threshold (exp2 domain)

    float qv[8], wev[8];
    {
        uint4 qw = *(const uint4*)(q32 + (size_t)wid * 64 + 4 * ln);
#pragma unroll
        for (int t = 0; t < 4; ++t) {
            unsigned u = ((const unsigned*)&qw)[t];
            qv[2 * t] = bf2f((unsigned short)u) * SC;
            qv[2 * t + 1] = bf2f((unsigned short)(u >> 16)) * SC;
        }
        float4 wlo = *(const float4*)(We + 8 * ln);
        float4 whi = *(const float4*)(We + 8 * ln + 4);
        wev[0] = wlo.x; wev[1] = wlo.y; wev[2] = wlo.z; wev[3] = wlo.w;
        wev[4] = whi.x; wev[5] = whi.y; wev[6] = whi.z; wev[7] = whi.w;
    }
    float qwe = 0.f;
#pragma unroll
    for (int i = 0; i < 8; ++i) qwe = fmaf(qv[i], wev[i], qwe);
    qwe += __shfl_xor(qwe, 1);
    qwe += __shfl_xor(qwe, 2);  // per-head q·we (scaled)

    float m = -1e30f, sden = 0.f, tacc = 0.f;
    float acc[8] = {};
    const unsigned* kvp = kv + 4 * ln;

    for (int cbse = base; cbse < end; cbse += 64) {
        int cnt = min(end - cbse, 64);
        int s_l = 0;
        float a_l = 0.f;
        if (lane < cnt) {
            int2 sa = esrc[cbse + lane];
            s_l = sa.x;
            a_l = __int_as_float(sa.y);
        }
        int jmax = (cnt + 3) >> 2;
        for (int j = 0; j < jmax; ++j) {
            int slot = j * 4 + g;
            bool valid = slot < cnt;
            int sN = __shfl(s_l, slot);
            float av = __shfl(a_l, slot);
            if (!valid) sN = 0;
            uint4 kvw = *(const uint4*)(kvp + (size_t)sN * 64);
            float vj[8];
            float p = 0.f;
#pragma unroll
            for (int t = 0; t < 4; ++t) {
                unsigned u = ((const unsigned*)&kvw)[t];
                f32x2 kk = __builtin_amdgcn_cvt_pk_f32_fp8((int)u, false);
                f32x2 vv = __builtin_amdgcn_cvt_pk_f32_fp8((int)u, true);
                p = fmaf(qv[2 * t], kk.x, p);
                p = fmaf(qv[2 * t + 1], kk.y, p);
                vj[2 * t] = vv.x;
                vj[2 * t + 1] = vv.y;
            }
            p += __shfl_xor(p, 1);
            p += __shfl_xor(p, 2);
            p = fmaf(av, qwe, p);
            p = valid ? p : -3e38f;
            if (__all(p - m <= THR)) {  // common path: no max update, no rescale
                float wgt = exp2f(p - m);
                sden += wgt;
                tacc = fmaf(wgt, av, tacc);
#pragma unroll
                for (int i = 0; i < 8; ++i) acc[i] = fmaf(wgt, vj[i], acc[i]);
            } else {
                float mn = fmaxf(m, p);
                float wgt = exp2f(p - mn);
                float sc = exp2f(m - mn);
                sden = fmaf(sden, sc, wgt);
                tacc = fmaf(tacc, sc, wgt * av);
#pragma unroll
                for (int i = 0; i < 8; ++i) acc[i] = fmaf(acc[i], sc, wgt * vj[i]);
                m = mn;
            }
        }
    }

    // merge the 4 subgroup partial states (lanes ln, ln+16, ln+32, ln+48 share channels & head)
#pragma unroll
    for (int off = 16; off <= 32; off <<= 1) {
        float m_o = __shfl_xor(m, off);
        float sden_o = __shfl_xor(sden, off);
        float t_o = __shfl_xor(tacc, off);
        float mn = fmaxf(m, m_o);
        float sa = exp2f(m - mn), sb = exp2f(m_o - mn);
        sden = sden * sa + sden_o * sb;
        tacc = tacc * sa + t_o * sb;
#pragma unroll
        for (int i = 0; i < 8; ++i) acc[i] = acc[i] * sa + __shfl_xor(acc[i], off) * sb;
        m = mn;
    }
    float rden = 1.f / (sden + 1e-16f);
    if (g == 0) {
#pragma unroll
        for (int i = 0; i < 8; ++i) sh_o[wv][8 * ln + i] = fmaf(tacc, wev[i], acc[i]) * rden;
    }
    __asm__ volatile("s_waitcnt lgkmcnt(0)" ::: "memory");  // same-wave LDS RAW

    // ---- epilogue: lane owns channels (2*lane, 2*lane+1) ----
    const int c0 = 2 * lane;
    const float2 ov0v = *(const float2*)(&sh_o[wv][c0]);
    float o0 = ov0v.x, o1 = ov0v.y;
    const unsigned xw = xr32[(size_t)wid * 64 + lane];
    const float x0 = bf2f((unsigned short)xw), x1 = bf2f((unsigned short)(xw >> 16));
    const float2 w0 = *(const float2*)(Wb + c0);
    const float2 w1 = *(const float2*)(Wb + 128 + c0);
    const float2 w2 = *(const float2*)(Wb + 256 + c0);
    float bl = o0 * w0.x + o1 * w0.y + x0 * w1.x + x1 * w1.y + (o0 - x0) * w2.x + (o1 - x1) * w2.y;
#pragma unroll
    for (int off = 32; off; off >>= 1) bl += __shfl_xor(bl, off);
    float beta = 1.f / (1.f + __expf(-bl));
    float g0 = beta * x0 + (1.f - beta) * o0;
    float g1 = beta * x1 + (1.f - beta) * o1;
    g0 = 0.5f * g0 * (1.f + erff(g0 * 0.70710678118654752f));
    g1 = 0.5f * g1 * (1.f + erff(g1 * 0.70710678118654752f));
    const unsigned rw = res32[(size_t)wid * 64 + lane];
    float t0 = g0 + bf2f((unsigned short)rw);
    float t1 = g1 + bf2f((unsigned short)(rw >> 16));
    float su = t0 + t1, sq = t0 * t0 + t1 * t1;
#pragma unroll
    for (int off = 32; off; off >>= 1) {
        su += __shfl_xor(su, off);
        sq += __shfl_xor(sq, off);
    }
    float mu = su * (1.f / 128.f);
    float var = sq * (1.f / 128.f) - mu * mu;
    float inv = rsqrtf(var + 1e-5f);
    const float2 gv = *(const float2*)(lng + c0);
    const float2 bv2 = *(const float2*)(lnb + c0);
    float ovx = (t0 - mu) * inv * gv.x + bv2.x;
    float ovy = (t1 - mu) * inv * gv.y + bv2.y;
    if (houtf) {
        *(float2*)(houtf + (size_t)wid * 128 + c0) = make_float2(ovx, ovy);
    } else {
        houtb[(size_t)wid * 64 + lane] = packbf(ovx, ovy);
    }
}

extern "C" void kernel_launch(void* const* d_in, const int* in_sizes, int n_in, void* d_out, int out_size,
                              void* d_ws, size_t ws_size, hipStream_t stream) {
    const float* x = (const float*)d_in[0];
    const int* ei = (const int*)d_in[1];
    const float* ea = (const float*)d_in[2];
    const float* Wi = (const float*)d_in[3];
    const float* bi = (const float*)d_in[4];
    const float* Wq = (const float*)d_in[5];
    const float* bq = (const float*)d_in[6];
    const float* Wk = (const float*)d_in[7];
    const float* bk = (const float*)d_in[8];
    const float* Wv = (const float*)d_in[9];
    const float* bv = (const float*)d_in[10];
    const float* We = (const float*)d_in[11];
    const float* Wskip = (const float*)d_in[12];
    const float* bskip = (const float*)d_in[13];
    const float* Wbeta = (const float*)d_in[14];
    const float* lng = (const float*)d_in[15];
    const float* lnb = (const float*)d_in[16];

    const int* srcp = ei;
    const int* dstp = ei + NEDGES;

    char* p = (char*)d_ws;
    auto alloc = [&](size_t bytes) {
        void* r = (void*)p;
        p += (bytes + 255) & ~(size_t)255;
        return r;
    };
    unsigned* h32 = (unsigned*)alloc((size_t)NNODES * 64 * 4);
    unsigned* q32 = (unsigned*)alloc((size_t)NNODES * 64 * 4);
    unsigned* xr32 = (unsigned*)alloc((size_t)NNODES * 64 * 4);
    unsigned* kv = (unsigned*)alloc((size_t)NNODES * 64 * 4);
    unsigned short* Wit = (unsigned short*)alloc((size_t)DHID * DIN * 2);
    unsigned short* Wt3 = (unsigned short*)alloc((size_t)3 * 512 * DHID * 2);
    int* counts = (int*)alloc((size_t)NNODES * 4);
    int* row_ptr = (int*)alloc((size_t)(NNODES + 1) * 4);
    int2* esrc = (int2*)alloc((size_t)NEDGES * 8);
    int* partials = (int*)alloc(256 * 4);

    const int EB = (NEDGES + 255) / 256;
    const int NB = (NNODES + 255) / 256;
    const int GB = (NNODES + 127) / 128;  // 391
    const int WB = (NNODES + 3) / 4;      // 12500 (4 waves/block, 1 node/wave)
    const int PB = (DHID * DIN + 3 * 512 * DHID + 255) / 256;

    prep_w<<<PB, 256, 0, stream>>>(Wi, Wq, Wk, Wv, Wskip, Wit, Wt3);

    // CSR by dst (single memset; scatter consumes the degree histogram via atomicSub)
    hipMemsetAsync(counts, 0, (size_t)NNODES * 4, stream);
    k_hist<<<EB, 256, 0, stream>>>(dstp, counts);
    k_scan_block<<<NB, 256, 0, stream>>>(counts, row_ptr + 1, partials, NNODES);
    k_scan_partials<<<1, 256, 0, stream>>>(partials, NB);
    k_apply<<<NB, 256, 0, stream>>>(partials, row_ptr, NNODES);
    k_scatter<<<EB, 256, 0, stream>>>(srcp, dstp, ea, row_ptr, counts, esrc);

    gemm_in<<<GB, 256, 0, stream>>>(x, Wit, bi, h32, NNODES);

    for (int l = 0; l < 3; ++l) {
        const size_t bo = (size_t)l * 128;
        gemm_qkvs<<<GB, 512, 0, stream>>>((const unsigned short*)h32, Wt3 + (size_t)l * 512 * DHID, bq + bo, bk + bo,
                                          bv + bo, bskip + bo, q32, kv, xr32, NNODES);
        node_attn_fuse<<<WB, 256, 0, stream>>>(q32, kv, esrc, We + bo, row_ptr, xr32, h32,
                                               Wbeta + (size_t)l * 384, lng + bo, lnb + bo, h32,
                                               (l == 2) ? (float*)d_out : nullptr);
    }
}